// Round 1
// baseline (1200.686 us; speedup 1.0000x reference)
//
#include <hip/hip_runtime.h>

#define BB 8
#define CC 64
#define HH 128
#define WW 128
#define HWSZ (HH*WW)

// ---------------- g MLP: g = relu(bsize@gw1.T+gb1)@gw2.T+gb2 ----------------
__global__ __launch_bounds__(512) void g_mlp_kernel(
    const float* __restrict__ bsize, const float* __restrict__ gw1,
    const float* __restrict__ gb1, const float* __restrict__ gw2,
    const float* __restrict__ gb2, float* __restrict__ g) {
  __shared__ float h[BB][64];
  int t = threadIdx.x;
  if (t < BB * 64) {
    int b = t >> 6, i = t & 63;
    float v = fmaf(bsize[b * 2 + 0], gw1[i * 2 + 0],
                   fmaf(bsize[b * 2 + 1], gw1[i * 2 + 1], gb1[i]));
    h[b][i] = fmaxf(v, 0.f);
  }
  __syncthreads();
  if (t < BB * 32) {
    int b = t >> 5, j = t & 31;
    float acc = gb2[j];
#pragma unroll
    for (int i = 0; i < 64; ++i) acc = fmaf(h[b][i], gw2[j * 64 + i], acc);
    g[b * 32 + j] = acc;
  }
}

// ---------------- generic 3x3 SAME conv, NCHW ----------------
// thread: 4 horizontal pixels x 4 output channels
template <int CIN, bool RELU>
__global__ __launch_bounds__(256) void conv3x3_kernel(
    const float* __restrict__ in, const float* __restrict__ wgt,
    const float* __restrict__ bias, float* __restrict__ out, int Cout) {
  __shared__ float sw[4 * CIN * 9];
  const int b = blockIdx.z;
  const int oc0 = blockIdx.y * 4;
  const int nw = min(4, Cout - oc0);
  for (int i = threadIdx.x; i < 4 * CIN * 9; i += 256)
    sw[i] = (i < nw * CIN * 9) ? wgt[oc0 * CIN * 9 + i] : 0.f;
  __syncthreads();
  const int strip = blockIdx.x * 256 + threadIdx.x;
  const int p0 = strip * 4;
  const int h = p0 >> 7;
  const int w0 = p0 & 127;
  float acc[4][4];
#pragma unroll
  for (int u = 0; u < 4; ++u) {
    float bv = (oc0 + u < Cout) ? bias[oc0 + u] : 0.f;
#pragma unroll
    for (int x = 0; x < 4; ++x) acc[u][x] = bv;
  }
  const float* inb = in + (size_t)b * CIN * HWSZ;
  for (int ic = 0; ic < CIN; ++ic) {
    const float* inc = inb + ic * HWSZ;
    float v[3][6];
#pragma unroll
    for (int r = 0; r < 3; ++r) {
      int yy = h + r - 1;
      bool yok = (unsigned)yy < HH;
#pragma unroll
      for (int ci = 0; ci < 6; ++ci) {
        int xx = w0 + ci - 1;
        bool ok = yok && ((unsigned)xx < WW);
        v[r][ci] = ok ? inc[yy * WW + xx] : 0.f;
      }
    }
#pragma unroll
    for (int u = 0; u < 4; ++u) {
      const float* wk = &sw[(u * CIN + ic) * 9];
#pragma unroll
      for (int r = 0; r < 3; ++r)
#pragma unroll
        for (int kj = 0; kj < 3; ++kj) {
          float wv = wk[r * 3 + kj];
#pragma unroll
          for (int x = 0; x < 4; ++x)
            acc[u][x] = fmaf(v[r][x + kj], wv, acc[u][x]);
        }
    }
  }
  float* outp = out + ((size_t)b * Cout + oc0) * HWSZ + p0;
#pragma unroll
  for (int u = 0; u < 4; ++u) {
    if (oc0 + u < Cout) {
#pragma unroll
      for (int x = 0; x < 4; ++x) {
        float val = acc[u][x];
        if (RELU) val = fmaxf(val, 0.f);
        outp[u * HWSZ + x] = val;
      }
    }
  }
}

// ---- fused conv: in = concat(g broadcast (32ch), l_offset (32ch)), Cout=32, relu ----
__global__ __launch_bounds__(256) void fused_conv_kernel(
    const float* __restrict__ loff, const float* __restrict__ g,
    const float* __restrict__ wgt /*[32][64][9]*/, const float* __restrict__ bias,
    float* __restrict__ out) {
  __shared__ float sw[4 * 64 * 9];
  const int b = blockIdx.z;
  const int oc0 = blockIdx.y * 4;
  for (int i = threadIdx.x; i < 4 * 64 * 9; i += 256)
    sw[i] = wgt[oc0 * 64 * 9 + i];
  __syncthreads();
  const int strip = blockIdx.x * 256 + threadIdx.x;
  const int p0 = strip * 4;
  const int h = p0 >> 7;
  const int w0 = p0 & 127;
  float acc[4][4];
#pragma unroll
  for (int u = 0; u < 4; ++u) {
    float bv = bias[oc0 + u];
#pragma unroll
    for (int x = 0; x < 4; ++x) acc[u][x] = bv;
  }
  // validity mask of the 3x6 input patch (same for all channels)
  bool okm[3][6];
#pragma unroll
  for (int r = 0; r < 3; ++r) {
    int yy = h + r - 1;
    bool yok = (unsigned)yy < HH;
#pragma unroll
    for (int ci = 0; ci < 6; ++ci) {
      int xx = w0 + ci - 1;
      okm[r][ci] = yok && ((unsigned)xx < WW);
    }
  }
  // channels 0..31: g (spatially constant, zero outside image)
  for (int ic = 0; ic < 32; ++ic) {
    float gv = g[b * 32 + ic];
    float v[3][6];
#pragma unroll
    for (int r = 0; r < 3; ++r)
#pragma unroll
      for (int ci = 0; ci < 6; ++ci) v[r][ci] = okm[r][ci] ? gv : 0.f;
#pragma unroll
    for (int u = 0; u < 4; ++u) {
      const float* wk = &sw[(u * 64 + ic) * 9];
#pragma unroll
      for (int r = 0; r < 3; ++r)
#pragma unroll
        for (int kj = 0; kj < 3; ++kj) {
          float wv = wk[r * 3 + kj];
#pragma unroll
          for (int x = 0; x < 4; ++x)
            acc[u][x] = fmaf(v[r][x + kj], wv, acc[u][x]);
        }
    }
  }
  // channels 32..63: l_offset
  const float* inb = loff + (size_t)b * 32 * HWSZ;
  for (int ic = 32; ic < 64; ++ic) {
    const float* inc = inb + (ic - 32) * HWSZ;
    float v[3][6];
#pragma unroll
    for (int r = 0; r < 3; ++r) {
      int yy = h + r - 1;
      bool yok = (unsigned)yy < HH;
#pragma unroll
      for (int ci = 0; ci < 6; ++ci) {
        int xx = w0 + ci - 1;
        bool ok = yok && ((unsigned)xx < WW);
        v[r][ci] = ok ? inc[yy * WW + xx] : 0.f;
      }
    }
#pragma unroll
    for (int u = 0; u < 4; ++u) {
      const float* wk = &sw[(u * 64 + ic) * 9];
#pragma unroll
      for (int r = 0; r < 3; ++r)
#pragma unroll
        for (int kj = 0; kj < 3; ++kj) {
          float wv = wk[r * 3 + kj];
#pragma unroll
          for (int x = 0; x < 4; ++x)
            acc[u][x] = fmaf(v[r][x + kj], wv, acc[u][x]);
        }
    }
  }
  float* outp = out + ((size_t)b * 32 + oc0) * HWSZ + p0;
#pragma unroll
  for (int u = 0; u < 4; ++u)
#pragma unroll
    for (int x = 0; x < 4; ++x)
      outp[u * HWSZ + x] = fmaxf(acc[u][x], 0.f);
}

// ---------------- deformable conv + bias + relu ----------------
// thread: 1 pixel, all 64 output channels in registers
__global__ __launch_bounds__(256) void deform_kernel(
    const float* __restrict__ x, const float* __restrict__ offset,
    const float* __restrict__ dw, const float* __restrict__ db,
    float* __restrict__ out) {
  __shared__ float sdw[64 * 64];  // [c][o] for tap k
  const int b = blockIdx.y;
  const int p = blockIdx.x * 256 + threadIdx.x;
  const int h = p >> 7, w = p & 127;
  float acc[64];
#pragma unroll
  for (int o = 0; o < 64; ++o) acc[o] = db[o];
  const float* xb = x + (size_t)b * CC * HWSZ;
  const float* offb = offset + (size_t)b * 18 * HWSZ + p;
  for (int k = 0; k < 9; ++k) {
    if (k) __syncthreads();
    for (int i = threadIdx.x; i < 64 * 64; i += 256) {
      int c = i >> 6, o = i & 63;
      sdw[i] = dw[(o * 64 + c) * 9 + k];
    }
    __syncthreads();
    float dy = offb[(2 * k) * HWSZ];
    float dx = offb[(2 * k + 1) * HWSZ];
    float py = (float)(h + k / 3 - 1) + dy;
    float px = (float)(w + k % 3 - 1) + dx;
    float y0f = floorf(py), x0f = floorf(px);
    float wy1 = py - y0f, wy0 = 1.f - wy1;
    float wx1 = px - x0f, wx0 = 1.f - wx1;
    int y0 = (int)y0f, x0 = (int)x0f;
    int y1 = y0 + 1, x1 = x0 + 1;
    bool y0ok = (unsigned)y0 < HH, y1ok = (unsigned)y1 < HH;
    bool x0ok = (unsigned)x0 < WW, x1ok = (unsigned)x1 < WW;
    float w00 = (y0ok && x0ok) ? wy0 * wx0 : 0.f;
    float w01 = (y0ok && x1ok) ? wy0 * wx1 : 0.f;
    float w10 = (y1ok && x0ok) ? wy1 * wx0 : 0.f;
    float w11 = (y1ok && x1ok) ? wy1 * wx1 : 0.f;
    int y0c = min(max(y0, 0), HH - 1), y1c = min(max(y1, 0), HH - 1);
    int x0c = min(max(x0, 0), WW - 1), x1c = min(max(x1, 0), WW - 1);
    int i00 = y0c * WW + x0c, i01 = y0c * WW + x1c;
    int i10 = y1c * WW + x0c, i11 = y1c * WW + x1c;
    for (int c = 0; c < 64; ++c) {
      const float* xc = xb + c * HWSZ;
      float s = w00 * xc[i00] + w01 * xc[i01] + w10 * xc[i10] + w11 * xc[i11];
      const float4* wrow = (const float4*)&sdw[c * 64];
#pragma unroll
      for (int og = 0; og < 16; ++og) {
        float4 wv = wrow[og];
        acc[og * 4 + 0] = fmaf(s, wv.x, acc[og * 4 + 0]);
        acc[og * 4 + 1] = fmaf(s, wv.y, acc[og * 4 + 1]);
        acc[og * 4 + 2] = fmaf(s, wv.z, acc[og * 4 + 2]);
        acc[og * 4 + 3] = fmaf(s, wv.w, acc[og * 4 + 3]);
      }
    }
  }
  float* outp = out + (size_t)b * 64 * HWSZ + p;
#pragma unroll
  for (int o = 0; o < 64; ++o) outp[o * HWSZ] = fmaxf(acc[o], 0.f);
}

extern "C" void kernel_launch(void* const* d_in, const int* in_sizes, int n_in,
                              void* d_out, int out_size, void* d_ws, size_t ws_size,
                              hipStream_t stream) {
  const float* x     = (const float*)d_in[0];
  const float* bsize = (const float*)d_in[1];
  const float* gw1   = (const float*)d_in[2];
  const float* gb1   = (const float*)d_in[3];
  const float* gw2   = (const float*)d_in[4];
  const float* gb2   = (const float*)d_in[5];
  const float* lw1   = (const float*)d_in[6];
  const float* lb1   = (const float*)d_in[7];
  const float* lw2   = (const float*)d_in[8];
  const float* lb2   = (const float*)d_in[9];
  const float* fw1   = (const float*)d_in[10];
  const float* fb1   = (const float*)d_in[11];
  const float* fw2   = (const float*)d_in[12];
  const float* fb2   = (const float*)d_in[13];
  const float* dw    = (const float*)d_in[14];
  const float* db    = (const float*)d_in[15];
  float* out = (float*)d_out;
  float* gbuf = (float*)d_ws;           // 256 floats used
  float* buf  = (float*)d_ws + 512;     // 8*32*128*128 floats = 16.8MB

  // g = MLP(bsize)
  g_mlp_kernel<<<1, 512, 0, stream>>>(bsize, gw1, gb1, gw2, gb2, gbuf);
  // t1 = relu(conv(x, lw1)) -> out (scratch)
  conv3x3_kernel<64, true><<<dim3(16, 8, 8), 256, 0, stream>>>(x, lw1, lb1, out, 32);
  // l_offset = conv(t1, lw2) -> buf
  conv3x3_kernel<32, false><<<dim3(16, 8, 8), 256, 0, stream>>>(out, lw2, lb2, buf, 32);
  // t2 = relu(conv(concat(g, l_offset), fw1)) -> out
  fused_conv_kernel<<<dim3(16, 8, 8), 256, 0, stream>>>(buf, gbuf, fw1, fb1, out);
  // offset = conv(t2, fw2) -> buf   (Cout = 18)
  conv3x3_kernel<32, false><<<dim3(16, 5, 8), 256, 0, stream>>>(out, fw2, fb2, buf, 18);
  // out = relu(deform_conv(x, offset, dw) + db)
  deform_kernel<<<dim3(64, 8), 256, 0, stream>>>(x, buf, dw, db, out);
}

// Round 2
// 890.880 us; speedup vs baseline: 1.3478x; 1.3478x over previous
//
#include <hip/hip_runtime.h>

#define BB 8
#define CC 64
#define HH 128
#define WW 128
#define HWSZ (HH*WW)

typedef __attribute__((ext_vector_type(8))) short short8;
typedef __attribute__((ext_vector_type(4))) float f32x4;

__device__ __forceinline__ unsigned short f2bf(float f) {
  union { float f; unsigned u; } un; un.f = f;
  unsigned u = un.u;
  u += 0x7fff + ((u >> 16) & 1);  // RNE
  return (unsigned short)(u >> 16);
}

// ---------------- g MLP: g = relu(bsize@gw1.T+gb1)@gw2.T+gb2 ----------------
__global__ __launch_bounds__(512) void g_mlp_kernel(
    const float* __restrict__ bsize, const float* __restrict__ gw1,
    const float* __restrict__ gb1, const float* __restrict__ gw2,
    const float* __restrict__ gb2, float* __restrict__ g) {
  __shared__ float h[BB][64];
  int t = threadIdx.x;
  if (t < BB * 64) {
    int b = t >> 6, i = t & 63;
    float v = fmaf(bsize[b * 2 + 0], gw1[i * 2 + 0],
                   fmaf(bsize[b * 2 + 1], gw1[i * 2 + 1], gb1[i]));
    h[b][i] = fmaxf(v, 0.f);
  }
  __syncthreads();
  if (t < BB * 32) {
    int b = t >> 5, j = t & 31;
    float acc = gb2[j];
#pragma unroll
    for (int i = 0; i < 64; ++i) acc = fmaf(h[b][i], gw2[j * 64 + i], acc);
    g[b * 32 + j] = acc;
  }
}

// ---------------- generic 3x3 SAME conv, NCHW ----------------
template <int CIN, bool RELU>
__global__ __launch_bounds__(256) void conv3x3_kernel(
    const float* __restrict__ in, const float* __restrict__ wgt,
    const float* __restrict__ bias, float* __restrict__ out, int Cout) {
  __shared__ float sw[4 * CIN * 9];
  const int b = blockIdx.z;
  const int oc0 = blockIdx.y * 4;
  const int nw = min(4, Cout - oc0);
  for (int i = threadIdx.x; i < 4 * CIN * 9; i += 256)
    sw[i] = (i < nw * CIN * 9) ? wgt[oc0 * CIN * 9 + i] : 0.f;
  __syncthreads();
  const int strip = blockIdx.x * 256 + threadIdx.x;
  const int p0 = strip * 4;
  const int h = p0 >> 7;
  const int w0 = p0 & 127;
  float acc[4][4];
#pragma unroll
  for (int u = 0; u < 4; ++u) {
    float bv = (oc0 + u < Cout) ? bias[oc0 + u] : 0.f;
#pragma unroll
    for (int x = 0; x < 4; ++x) acc[u][x] = bv;
  }
  const float* inb = in + (size_t)b * CIN * HWSZ;
  for (int ic = 0; ic < CIN; ++ic) {
    const float* inc = inb + ic * HWSZ;
    float v[3][6];
#pragma unroll
    for (int r = 0; r < 3; ++r) {
      int yy = h + r - 1;
      bool yok = (unsigned)yy < HH;
#pragma unroll
      for (int ci = 0; ci < 6; ++ci) {
        int xx = w0 + ci - 1;
        bool ok = yok && ((unsigned)xx < WW);
        v[r][ci] = ok ? inc[yy * WW + xx] : 0.f;
      }
    }
#pragma unroll
    for (int u = 0; u < 4; ++u) {
      const float* wk = &sw[(u * CIN + ic) * 9];
#pragma unroll
      for (int r = 0; r < 3; ++r)
#pragma unroll
        for (int kj = 0; kj < 3; ++kj) {
          float wv = wk[r * 3 + kj];
#pragma unroll
          for (int x = 0; x < 4; ++x)
            acc[u][x] = fmaf(v[r][x + kj], wv, acc[u][x]);
        }
    }
  }
  float* outp = out + ((size_t)b * Cout + oc0) * HWSZ + p0;
#pragma unroll
  for (int u = 0; u < 4; ++u) {
    if (oc0 + u < Cout) {
#pragma unroll
      for (int x = 0; x < 4; ++x) {
        float val = acc[u][x];
        if (RELU) val = fmaxf(val, 0.f);
        outp[u * HWSZ + x] = val;
      }
    }
  }
}

// ---- fused conv: in = concat(g broadcast (32ch), l_offset (32ch)), Cout=32, relu ----
__global__ __launch_bounds__(256) void fused_conv_kernel(
    const float* __restrict__ loff, const float* __restrict__ g,
    const float* __restrict__ wgt, const float* __restrict__ bias,
    float* __restrict__ out) {
  __shared__ float sw[4 * 64 * 9];
  const int b = blockIdx.z;
  const int oc0 = blockIdx.y * 4;
  for (int i = threadIdx.x; i < 4 * 64 * 9; i += 256)
    sw[i] = wgt[oc0 * 64 * 9 + i];
  __syncthreads();
  const int strip = blockIdx.x * 256 + threadIdx.x;
  const int p0 = strip * 4;
  const int h = p0 >> 7;
  const int w0 = p0 & 127;
  float acc[4][4];
#pragma unroll
  for (int u = 0; u < 4; ++u) {
    float bv = bias[oc0 + u];
#pragma unroll
    for (int x = 0; x < 4; ++x) acc[u][x] = bv;
  }
  bool okm[3][6];
#pragma unroll
  for (int r = 0; r < 3; ++r) {
    int yy = h + r - 1;
    bool yok = (unsigned)yy < HH;
#pragma unroll
    for (int ci = 0; ci < 6; ++ci) {
      int xx = w0 + ci - 1;
      okm[r][ci] = yok && ((unsigned)xx < WW);
    }
  }
  for (int ic = 0; ic < 32; ++ic) {
    float gv = g[b * 32 + ic];
    float v[3][6];
#pragma unroll
    for (int r = 0; r < 3; ++r)
#pragma unroll
      for (int ci = 0; ci < 6; ++ci) v[r][ci] = okm[r][ci] ? gv : 0.f;
#pragma unroll
    for (int u = 0; u < 4; ++u) {
      const float* wk = &sw[(u * 64 + ic) * 9];
#pragma unroll
      for (int r = 0; r < 3; ++r)
#pragma unroll
        for (int kj = 0; kj < 3; ++kj) {
          float wv = wk[r * 3 + kj];
#pragma unroll
          for (int x = 0; x < 4; ++x)
            acc[u][x] = fmaf(v[r][x + kj], wv, acc[u][x]);
        }
    }
  }
  const float* inb = loff + (size_t)b * 32 * HWSZ;
  for (int ic = 32; ic < 64; ++ic) {
    const float* inc = inb + (ic - 32) * HWSZ;
    float v[3][6];
#pragma unroll
    for (int r = 0; r < 3; ++r) {
      int yy = h + r - 1;
      bool yok = (unsigned)yy < HH;
#pragma unroll
      for (int ci = 0; ci < 6; ++ci) {
        int xx = w0 + ci - 1;
        bool ok = yok && ((unsigned)xx < WW);
        v[r][ci] = ok ? inc[yy * WW + xx] : 0.f;
      }
    }
#pragma unroll
    for (int u = 0; u < 4; ++u) {
      const float* wk = &sw[(u * 64 + ic) * 9];
#pragma unroll
      for (int r = 0; r < 3; ++r)
#pragma unroll
        for (int kj = 0; kj < 3; ++kj) {
          float wv = wk[r * 3 + kj];
#pragma unroll
          for (int x = 0; x < 4; ++x)
            acc[u][x] = fmaf(v[r][x + kj], wv, acc[u][x]);
        }
    }
  }
  float* outp = out + ((size_t)b * 32 + oc0) * HWSZ + p0;
#pragma unroll
  for (int u = 0; u < 4; ++u)
#pragma unroll
    for (int x = 0; x < 4; ++x)
      outp[u * HWSZ + x] = fmaxf(acc[u][x], 0.f);
}

// ---- weight reorder for deform MFMA: wbf[o][kt*64 + c] = bf16(dw[o][c][kt]) ----
__global__ __launch_bounds__(256) void wprep_kernel(
    const float* __restrict__ dw, unsigned short* __restrict__ wbf) {
  int i = blockIdx.x * 256 + threadIdx.x;
  if (i >= 64 * 576) return;
  int o = i / 576, K = i - o * 576;
  int kt = K >> 6, c = K & 63;
  wbf[i] = f2bf(dw[(o * 64 + c) * 9 + kt]);
}

// ---------------- deformable conv via MFMA, no LDS ----------------
// block = 4 waves = one (batch, image row). wave owns 64 o x 32 px.
// D[o][p] = A[o][K] * B[K][p], K = kt*64 + c (576 total).
// A frag: lane holds A[row=l&15][k=(l>>4)*8+i]  (16B from wbf row)
// B frag: lane holds B[k=(l>>4)*8+i][col=l&15]  (8 bilinear samples, in-reg)
// C/D:    col=lane&15, row=(lane>>4)*4+reg   (verified layout)
__global__ __launch_bounds__(256) void deform_mfma_kernel(
    const float* __restrict__ x, const float* __restrict__ offset,
    const unsigned short* __restrict__ wbf, const float* __restrict__ db,
    float* __restrict__ out) {
  const int b = blockIdx.y;
  const int h = blockIdx.x;
  const int lane = threadIdx.x & 63;
  const int wave = threadIdx.x >> 6;
  const int l15 = lane & 15, l4 = lane >> 4;
  const float* xb = x + (size_t)b * CC * HWSZ;
  const float* offb = offset + (size_t)b * 18 * HWSZ + h * WW;

  f32x4 acc[4][2];
#pragma unroll
  for (int f = 0; f < 4; ++f)
#pragma unroll
    for (int j = 0; j < 2; ++j) acc[f][j] = (f32x4){0.f, 0.f, 0.f, 0.f};

  for (int kt = 0; kt < 9; ++kt) {
    const int ki = kt / 3 - 1, kj = kt % 3 - 1;
    int ibase[2][4];
    float cw[2][4];
#pragma unroll
    for (int j = 0; j < 2; ++j) {
      int wpix = wave * 32 + j * 16 + l15;
      float dy = offb[(size_t)(2 * kt) * HWSZ + wpix];
      float dx = offb[(size_t)(2 * kt + 1) * HWSZ + wpix];
      float py = (float)(h + ki) + dy;
      float px = (float)(wpix + kj) + dx;
      float y0f = floorf(py), x0f = floorf(px);
      float wy1 = py - y0f, wy0 = 1.f - wy1;
      float wx1 = px - x0f, wx0 = 1.f - wx1;
      int y0 = (int)y0f, x0i = (int)x0f;
      int y1 = y0 + 1, x1i = x0i + 1;
      bool y0ok = (unsigned)y0 < HH, y1ok = (unsigned)y1 < HH;
      bool x0ok = (unsigned)x0i < WW, x1ok = (unsigned)x1i < WW;
      cw[j][0] = (y0ok && x0ok) ? wy0 * wx0 : 0.f;
      cw[j][1] = (y0ok && x1ok) ? wy0 * wx1 : 0.f;
      cw[j][2] = (y1ok && x0ok) ? wy1 * wx0 : 0.f;
      cw[j][3] = (y1ok && x1ok) ? wy1 * wx1 : 0.f;
      int y0c = min(max(y0, 0), HH - 1), y1c = min(max(y1, 0), HH - 1);
      int x0c = min(max(x0i, 0), WW - 1), x1c = min(max(x1i, 0), WW - 1);
      ibase[j][0] = y0c * WW + x0c;
      ibase[j][1] = y0c * WW + x1c;
      ibase[j][2] = y1c * WW + x0c;
      ibase[j][3] = y1c * WW + x1c;
    }
#pragma unroll
    for (int ch = 0; ch < 2; ++ch) {
      const int c0 = ch * 32 + l4 * 8;
      short8 afr[4];
      const unsigned short* wrow = wbf + kt * 64 + ch * 32 + l4 * 8;
#pragma unroll
      for (int f = 0; f < 4; ++f)
        afr[f] = *(const short8*)(wrow + (size_t)(f * 16 + l15) * 576);
#pragma unroll
      for (int j = 0; j < 2; ++j) {
        const float* p00 = xb + (size_t)c0 * HWSZ + ibase[j][0];
        const float* p01 = xb + (size_t)c0 * HWSZ + ibase[j][1];
        const float* p10 = xb + (size_t)c0 * HWSZ + ibase[j][2];
        const float* p11 = xb + (size_t)c0 * HWSZ + ibase[j][3];
        float w00 = cw[j][0], w01 = cw[j][1], w10 = cw[j][2], w11 = cw[j][3];
        short8 bv;
#pragma unroll
        for (int i = 0; i < 8; ++i) {
          float s = w00 * p00[i * HWSZ] + w01 * p01[i * HWSZ]
                  + w10 * p10[i * HWSZ] + w11 * p11[i * HWSZ];
          bv[i] = (short)f2bf(s);
        }
#pragma unroll
        for (int f = 0; f < 4; ++f)
          acc[f][j] = __builtin_amdgcn_mfma_f32_16x16x32_bf16(afr[f], bv, acc[f][j], 0, 0, 0);
      }
    }
  }
  float* outb = out + (size_t)b * CC * HWSZ + h * WW;
#pragma unroll
  for (int f = 0; f < 4; ++f)
#pragma unroll
    for (int j = 0; j < 2; ++j) {
      int wpix = wave * 32 + j * 16 + l15;
#pragma unroll
      for (int r = 0; r < 4; ++r) {
        int o = f * 16 + l4 * 4 + r;
        float v = acc[f][j][r] + db[o];
        outb[(size_t)o * HWSZ + wpix] = fmaxf(v, 0.f);
      }
    }
}

extern "C" void kernel_launch(void* const* d_in, const int* in_sizes, int n_in,
                              void* d_out, int out_size, void* d_ws, size_t ws_size,
                              hipStream_t stream) {
  const float* x     = (const float*)d_in[0];
  const float* bsize = (const float*)d_in[1];
  const float* gw1   = (const float*)d_in[2];
  const float* gb1   = (const float*)d_in[3];
  const float* gw2   = (const float*)d_in[4];
  const float* gb2   = (const float*)d_in[5];
  const float* lw1   = (const float*)d_in[6];
  const float* lb1   = (const float*)d_in[7];
  const float* lw2   = (const float*)d_in[8];
  const float* lb2   = (const float*)d_in[9];
  const float* fw1   = (const float*)d_in[10];
  const float* fb1   = (const float*)d_in[11];
  const float* fw2   = (const float*)d_in[12];
  const float* fb2   = (const float*)d_in[13];
  const float* dw    = (const float*)d_in[14];
  const float* db    = (const float*)d_in[15];
  float* out = (float*)d_out;
  float* gbuf = (float*)d_ws;           // 256 floats used
  float* buf  = (float*)d_ws + 512;     // 8*32*128*128 floats = 16.8MB
  // bf16 reordered deform weights live in the tail of buf (past the 18-ch
  // offset region): written after fused_conv has consumed l_offset.
  unsigned short* wbf = (unsigned short*)(buf + (size_t)BB * 18 * HWSZ);

  // g = MLP(bsize)
  g_mlp_kernel<<<1, 512, 0, stream>>>(bsize, gw1, gb1, gw2, gb2, gbuf);
  // t1 = relu(conv(x, lw1)) -> out (scratch)
  conv3x3_kernel<64, true><<<dim3(16, 8, 8), 256, 0, stream>>>(x, lw1, lb1, out, 32);
  // l_offset = conv(t1, lw2) -> buf
  conv3x3_kernel<32, false><<<dim3(16, 8, 8), 256, 0, stream>>>(out, lw2, lb2, buf, 32);
  // t2 = relu(conv(concat(g, l_offset), fw1)) -> out
  fused_conv_kernel<<<dim3(16, 8, 8), 256, 0, stream>>>(buf, gbuf, fw1, fb1, out);
  // reorder dw -> bf16 [o][kt*64+c]  (buf tail is free now)
  wprep_kernel<<<144, 256, 0, stream>>>(dw, wbf);
  // offset = conv(t2, fw2) -> buf[0:18ch]
  conv3x3_kernel<32, false><<<dim3(16, 5, 8), 256, 0, stream>>>(out, fw2, fb2, buf, 18);
  // out = relu(deform_conv(x, offset, dw) + db)  via MFMA
  deform_mfma_kernel<<<dim3(128, 8), 256, 0, stream>>>(x, buf, wbf, db, out);
}

// Round 3
// 225.929 us; speedup vs baseline: 5.3145x; 3.9432x over previous
//
#include <hip/hip_runtime.h>

#define BB 8
#define CC 64
#define HH 128
#define WW 128
#define HWSZ (HH*WW)

typedef __attribute__((ext_vector_type(8))) short short8;
typedef __attribute__((ext_vector_type(4))) short short4v;
typedef __attribute__((ext_vector_type(4))) float f32x4;

__device__ __forceinline__ unsigned short f2bf(float f) {
  union { float f; unsigned u; } un; un.f = f;
  unsigned u = un.u;
  u += 0x7fff + ((u >> 16) & 1);  // RNE
  return (unsigned short)(u >> 16);
}
__device__ __forceinline__ float bf2f(short s) {
  union { unsigned u; float f; } un;
  un.u = ((unsigned)(unsigned short)s) << 16;
  return un.f;
}

// ---------------- g MLP ----------------
__global__ __launch_bounds__(512) void g_mlp_kernel(
    const float* __restrict__ bsize, const float* __restrict__ gw1,
    const float* __restrict__ gb1, const float* __restrict__ gw2,
    const float* __restrict__ gb2, float* __restrict__ g) {
  __shared__ float h[BB][64];
  int t = threadIdx.x;
  if (t < BB * 64) {
    int b = t >> 6, i = t & 63;
    float v = fmaf(bsize[b * 2 + 0], gw1[i * 2 + 0],
                   fmaf(bsize[b * 2 + 1], gw1[i * 2 + 1], gb1[i]));
    h[b][i] = fmaxf(v, 0.f);
  }
  __syncthreads();
  if (t < BB * 32) {
    int b = t >> 5, j = t & 31;
    float acc = gb2[j];
#pragma unroll
    for (int i = 0; i < 64; ++i) acc = fmaf(h[b][i], gw2[j * 64 + i], acc);
    g[b * 32 + j] = acc;
  }
}

// ---- pack ALL weights to bf16 [o][kt*CIN+c] ----
// cwpk: lw1p[32][576] @0, lw2p[32][288] @18432, fw1p[32][576] @27648,
//       fw2p[32][288] @46080 (rows>=18 zero).  dwp: [64][576].
__global__ __launch_bounds__(256) void wprep_kernel(
    const float* __restrict__ lw1, const float* __restrict__ lw2,
    const float* __restrict__ fw1, const float* __restrict__ fw2,
    const float* __restrict__ dw, unsigned short* __restrict__ cwpk,
    unsigned short* __restrict__ dwp) {
  int i = blockIdx.x * 256 + threadIdx.x;
  if (i < 18432) {
    int o = i / 576, K = i - o * 576, kt = K >> 6, c = K & 63;
    cwpk[i] = f2bf(lw1[(o * 64 + c) * 9 + kt]);
  } else if (i < 27648) {
    int j = i - 18432;
    int o = j / 288, K = j - o * 288, kt = K >> 5, c = K & 31;
    cwpk[i] = f2bf(lw2[(o * 32 + c) * 9 + kt]);
  } else if (i < 46080) {
    int j = i - 27648;
    int o = j / 576, K = j - o * 576, kt = K >> 6, c = K & 63;
    cwpk[i] = f2bf(fw1[(o * 64 + c) * 9 + kt]);
  } else if (i < 55296) {
    int j = i - 46080;
    int o = j / 288, K = j - o * 288, kt = K >> 5, c = K & 31;
    cwpk[i] = (o < 18) ? f2bf(fw2[(o * 32 + c) * 9 + kt]) : (unsigned short)0;
  } else if (i < 92160) {
    int j = i - 55296;
    int o = j / 576, K = j - o * 576, kt = K >> 6, c = K & 63;
    dwp[j] = f2bf(dw[(o * 64 + c) * 9 + kt]);
  }
}

// ---- x -> channel-last bf16: xt[b][p][64] ----
__global__ __launch_bounds__(256) void xtprep_kernel(
    const float* __restrict__ x, unsigned short* __restrict__ xt) {
  int t = blockIdx.x * 256 + threadIdx.x;  // 8*16384 pixels
  int b = t >> 14, p = t & 16383;
  const float* xb = x + (size_t)b * 64 * HWSZ + p;
  unsigned short* ob = xt + (size_t)t * 64;
#pragma unroll
  for (int c0 = 0; c0 < 64; c0 += 8) {
    short8 v;
#pragma unroll
    for (int i = 0; i < 8; ++i) v[i] = (short)f2bf(xb[(size_t)(c0 + i) * HWSZ]);
    *(short8*)(ob + c0) = v;
  }
}

// ---------------- conv 3x3 via MFMA, implicit GEMM ----------------
// block = 4 waves = one (b, row). wave: 32 px x 32 outputs.
// in: channel-last bf16 [b][p][CINS].  wpk: [32][9*CIN] bf16.
// GFUSE: K-group 0 is spatially-constant g (32 ch), group 1 reads `in`.
template <int CINS, int NCG, bool GFUSE, bool RELU, bool CLOUT>
__global__ __launch_bounds__(256) void conv_mfma_kernel(
    const unsigned short* __restrict__ in, const unsigned short* __restrict__ wpk,
    const float* __restrict__ bias, const float* __restrict__ g,
    void* __restrict__ outv, int Cout) {
  constexpr int CIN = GFUSE ? 64 : NCG * 32;
  const int b = blockIdx.y, h = blockIdx.x;
  const int lane = threadIdx.x & 63, wave = threadIdx.x >> 6;
  const int l15 = lane & 15, l4 = lane >> 4;
  const unsigned short* inb = in + (size_t)b * HWSZ * CINS;
  const short8 zfr = {0, 0, 0, 0, 0, 0, 0, 0};
  short8 gfr = zfr;
  if (GFUSE) {
#pragma unroll
    for (int i = 0; i < 8; ++i) gfr[i] = (short)f2bf(g[b * 32 + l4 * 8 + i]);
  }
  f32x4 acc[2][2];
#pragma unroll
  for (int f = 0; f < 2; ++f)
#pragma unroll
    for (int j = 0; j < 2; ++j) acc[f][j] = (f32x4){0.f, 0.f, 0.f, 0.f};

  for (int kt = 0; kt < 9; ++kt) {
    const int ki = kt / 3 - 1, kj = kt % 3 - 1;
    const int y = h + ki;
    const bool yok = (unsigned)y < HH;
    const int yc = min(max(y, 0), HH - 1);
    int xs[2];
    bool ok[2];
#pragma unroll
    for (int j = 0; j < 2; ++j) {
      int xx = wave * 32 + j * 16 + l15 + kj;
      ok[j] = yok && ((unsigned)xx < WW);
      xs[j] = min(max(xx, 0), WW - 1);
    }
    const unsigned short* wr = wpk + kt * CIN + l4 * 8;
#pragma unroll
    for (int cg = 0; cg < NCG; ++cg) {
      short8 afr0 = *(const short8*)(wr + cg * 32 + (size_t)l15 * (9 * CIN));
      short8 afr1 = *(const short8*)(wr + cg * 32 + (size_t)(l15 + 16) * (9 * CIN));
#pragma unroll
      for (int j = 0; j < 2; ++j) {
        short8 bv;
        if (GFUSE && cg == 0) {
          bv = ok[j] ? gfr : zfr;
        } else {
          const int csrc = GFUSE ? 0 : cg * 32;
          short8 ld = *(const short8*)(inb + (size_t)(yc * WW + xs[j]) * CINS + csrc + l4 * 8);
          bv = ok[j] ? ld : zfr;
        }
        acc[0][j] = __builtin_amdgcn_mfma_f32_16x16x32_bf16(afr0, bv, acc[0][j], 0, 0, 0);
        acc[1][j] = __builtin_amdgcn_mfma_f32_16x16x32_bf16(afr1, bv, acc[1][j], 0, 0, 0);
      }
    }
  }
  if (CLOUT) {  // channel-last bf16, Cout==32
    unsigned short* ob = (unsigned short*)outv + (size_t)b * HWSZ * 32;
#pragma unroll
    for (int f = 0; f < 2; ++f)
#pragma unroll
      for (int j = 0; j < 2; ++j) {
        int p = h * WW + wave * 32 + j * 16 + l15;
        int o0 = f * 16 + l4 * 4;
        short4v st;
#pragma unroll
        for (int r = 0; r < 4; ++r) {
          float v = acc[f][j][r] + bias[o0 + r];
          if (RELU) v = fmaxf(v, 0.f);
          st[r] = (short)f2bf(v);
        }
        *(short4v*)(ob + (size_t)p * 32 + o0) = st;
      }
  } else {  // NCHW fp32
    float* ob = (float*)outv + (size_t)b * Cout * HWSZ;
#pragma unroll
    for (int f = 0; f < 2; ++f)
#pragma unroll
      for (int j = 0; j < 2; ++j) {
        int p = h * WW + wave * 32 + j * 16 + l15;
#pragma unroll
        for (int r = 0; r < 4; ++r) {
          int o = f * 16 + l4 * 4 + r;
          if (o < Cout) {
            float v = acc[f][j][r] + bias[o];
            if (RELU) v = fmaxf(v, 0.f);
            ob[(size_t)o * HWSZ + p] = v;
          }
        }
      }
  }
}

// ---------------- deformable conv via MFMA, channel-last x ----------------
__global__ __launch_bounds__(256) void deform_mfma_kernel(
    const unsigned short* __restrict__ xt, const float* __restrict__ offset,
    const unsigned short* __restrict__ dwp, const float* __restrict__ db,
    float* __restrict__ out) {
  const int b = blockIdx.y, h = blockIdx.x;
  const int lane = threadIdx.x & 63, wave = threadIdx.x >> 6;
  const int l15 = lane & 15, l4 = lane >> 4;
  const unsigned short* xb = xt + (size_t)b * HWSZ * 64;
  const float* offb = offset + (size_t)b * 18 * HWSZ + h * WW;

  f32x4 acc[4][2];
#pragma unroll
  for (int f = 0; f < 4; ++f)
#pragma unroll
    for (int j = 0; j < 2; ++j) acc[f][j] = (f32x4){0.f, 0.f, 0.f, 0.f};

  for (int kt = 0; kt < 9; ++kt) {
    const int ki = kt / 3 - 1, kj = kt % 3 - 1;
    int ib[2][4];
    float cw[2][4];
#pragma unroll
    for (int j = 0; j < 2; ++j) {
      int wpix = wave * 32 + j * 16 + l15;
      float dy = offb[(size_t)(2 * kt) * HWSZ + wpix];
      float dx = offb[(size_t)(2 * kt + 1) * HWSZ + wpix];
      float py = (float)(h + ki) + dy;
      float px = (float)(wpix + kj) + dx;
      float y0f = floorf(py), x0f = floorf(px);
      float wy1 = py - y0f, wy0 = 1.f - wy1;
      float wx1 = px - x0f, wx0 = 1.f - wx1;
      int y0 = (int)y0f, x0i = (int)x0f;
      int y1 = y0 + 1, x1i = x0i + 1;
      bool y0ok = (unsigned)y0 < HH, y1ok = (unsigned)y1 < HH;
      bool x0ok = (unsigned)x0i < WW, x1ok = (unsigned)x1i < WW;
      cw[j][0] = (y0ok && x0ok) ? wy0 * wx0 : 0.f;
      cw[j][1] = (y0ok && x1ok) ? wy0 * wx1 : 0.f;
      cw[j][2] = (y1ok && x0ok) ? wy1 * wx0 : 0.f;
      cw[j][3] = (y1ok && x1ok) ? wy1 * wx1 : 0.f;
      int y0c = min(max(y0, 0), HH - 1), y1c = min(max(y1, 0), HH - 1);
      int x0c = min(max(x0i, 0), WW - 1), x1c = min(max(x1i, 0), WW - 1);
      ib[j][0] = y0c * WW + x0c;
      ib[j][1] = y0c * WW + x1c;
      ib[j][2] = y1c * WW + x0c;
      ib[j][3] = y1c * WW + x1c;
    }
#pragma unroll
    for (int cg = 0; cg < 2; ++cg) {
      const unsigned short* wr = dwp + kt * 64 + cg * 32 + l4 * 8;
      short8 afr[4];
#pragma unroll
      for (int f = 0; f < 4; ++f)
        afr[f] = *(const short8*)(wr + (size_t)(f * 16 + l15) * 576);
      const unsigned short* cb = xb + cg * 32 + l4 * 8;
#pragma unroll
      for (int j = 0; j < 2; ++j) {
        short8 c00 = *(const short8*)(cb + (size_t)ib[j][0] * 64);
        short8 c01 = *(const short8*)(cb + (size_t)ib[j][1] * 64);
        short8 c10 = *(const short8*)(cb + (size_t)ib[j][2] * 64);
        short8 c11 = *(const short8*)(cb + (size_t)ib[j][3] * 64);
        float w00 = cw[j][0], w01 = cw[j][1], w10 = cw[j][2], w11 = cw[j][3];
        short8 bv;
#pragma unroll
        for (int i = 0; i < 8; ++i) {
          float s = w00 * bf2f(c00[i]) + w01 * bf2f(c01[i])
                  + w10 * bf2f(c10[i]) + w11 * bf2f(c11[i]);
          bv[i] = (short)f2bf(s);
        }
#pragma unroll
        for (int f = 0; f < 4; ++f)
          acc[f][j] = __builtin_amdgcn_mfma_f32_16x16x32_bf16(afr[f], bv, acc[f][j], 0, 0, 0);
      }
    }
  }
  float* outb = out + (size_t)b * CC * HWSZ + h * WW;
#pragma unroll
  for (int f = 0; f < 4; ++f)
#pragma unroll
    for (int j = 0; j < 2; ++j) {
      int wpix = wave * 32 + j * 16 + l15;
#pragma unroll
      for (int r = 0; r < 4; ++r) {
        int o = f * 16 + l4 * 4 + r;
        float v = acc[f][j][r] + db[o];
        outb[(size_t)o * HWSZ + wpix] = fmaxf(v, 0.f);
      }
    }
}

extern "C" void kernel_launch(void* const* d_in, const int* in_sizes, int n_in,
                              void* d_out, int out_size, void* d_ws, size_t ws_size,
                              hipStream_t stream) {
  const float* x     = (const float*)d_in[0];
  const float* bsize = (const float*)d_in[1];
  const float* gw1   = (const float*)d_in[2];
  const float* gb1   = (const float*)d_in[3];
  const float* gw2   = (const float*)d_in[4];
  const float* gb2   = (const float*)d_in[5];
  const float* lw1   = (const float*)d_in[6];
  const float* lb1   = (const float*)d_in[7];
  const float* lw2   = (const float*)d_in[8];
  const float* lb2   = (const float*)d_in[9];
  const float* fw1   = (const float*)d_in[10];
  const float* fb1   = (const float*)d_in[11];
  const float* fw2   = (const float*)d_in[12];
  const float* fb2   = (const float*)d_in[13];
  const float* dw    = (const float*)d_in[14];
  const float* db    = (const float*)d_in[15];
  float* out = (float*)d_out;

  // ws layout: gbuf(2KB) | xt bf16 8*16384*64 (16.8MB) | offset fp32 8*18*16384 (9.4MB) | dwp (74KB)
  float* gbuf = (float*)d_ws;
  unsigned short* xt = (unsigned short*)((char*)d_ws + 2048);
  float* offset = (float*)((char*)d_ws + 2048 + (size_t)BB * HWSZ * 64 * 2);
  unsigned short* dwp = (unsigned short*)((char*)offset + (size_t)BB * 18 * HWSZ * 4);

  // d_out scratch layout (all dead before deform writes out):
  //   loff bf16 CL [b][p][32] @0 (8.39MB) | cwpk (110KB) @8.39MB | t1/t2 bf16 CL @16.78MB
  unsigned short* loff = (unsigned short*)d_out;
  unsigned short* cwpk = (unsigned short*)d_out + 4194304;
  unsigned short* t12  = (unsigned short*)d_out + 8388608;
  const unsigned short* lw1p = cwpk;
  const unsigned short* lw2p = cwpk + 18432;
  const unsigned short* fw1p = cwpk + 27648;
  const unsigned short* fw2p = cwpk + 46080;

  g_mlp_kernel<<<1, 512, 0, stream>>>(bsize, gw1, gb1, gw2, gb2, gbuf);
  wprep_kernel<<<360, 256, 0, stream>>>(lw1, lw2, fw1, fw2, dw, cwpk, dwp);
  xtprep_kernel<<<512, 256, 0, stream>>>(x, xt);
  // t1 = relu(conv(x, lw1))
  conv_mfma_kernel<64, 2, false, true, true><<<dim3(128, 8), 256, 0, stream>>>(
      xt, lw1p, lb1, nullptr, t12, 32);
  // loff = conv(t1, lw2)
  conv_mfma_kernel<32, 1, false, false, true><<<dim3(128, 8), 256, 0, stream>>>(
      t12, lw2p, lb2, nullptr, loff, 32);
  // t2 = relu(conv(concat(g, loff), fw1))  (overwrites t1)
  conv_mfma_kernel<32, 2, true, true, true><<<dim3(128, 8), 256, 0, stream>>>(
      loff, fw1p, fb1, gbuf, t12, 32);
  // offset = conv(t2, fw2), Cout=18, NCHW fp32
  conv_mfma_kernel<32, 1, false, false, false><<<dim3(128, 8), 256, 0, stream>>>(
      t12, fw2p, fb2, nullptr, offset, 18);
  // out = relu(deform_conv(x, offset, dw) + db)
  deform_mfma_kernel<<<dim3(128, 8), 256, 0, stream>>>(xt, offset, dwp, db, out);
}

// Round 4
// 203.784 us; speedup vs baseline: 5.8920x; 1.1087x over previous
//
#include <hip/hip_runtime.h>

#define BB 8
#define CC 64
#define HH 128
#define WW 128
#define HWSZ (HH*WW)

typedef __attribute__((ext_vector_type(8))) short short8;
typedef __attribute__((ext_vector_type(4))) short short4v;
typedef __attribute__((ext_vector_type(4))) float f32x4;

__device__ __forceinline__ unsigned short f2bf(float f) {
  union { float f; unsigned u; } un; un.f = f;
  unsigned u = un.u;
  u += 0x7fff + ((u >> 16) & 1);  // RNE
  return (unsigned short)(u >> 16);
}
__device__ __forceinline__ float bf2f(short s) {
  union { unsigned u; float f; } un;
  un.u = ((unsigned)(unsigned short)s) << 16;
  return un.f;
}

// ---------------- g MLP ----------------
__global__ __launch_bounds__(512) void g_mlp_kernel(
    const float* __restrict__ bsize, const float* __restrict__ gw1,
    const float* __restrict__ gb1, const float* __restrict__ gw2,
    const float* __restrict__ gb2, float* __restrict__ g) {
  __shared__ float h[BB][64];
  int t = threadIdx.x;
  if (t < BB * 64) {
    int b = t >> 6, i = t & 63;
    float v = fmaf(bsize[b * 2 + 0], gw1[i * 2 + 0],
                   fmaf(bsize[b * 2 + 1], gw1[i * 2 + 1], gb1[i]));
    h[b][i] = fmaxf(v, 0.f);
  }
  __syncthreads();
  if (t < BB * 32) {
    int b = t >> 5, j = t & 31;
    float acc = gb2[j];
#pragma unroll
    for (int i = 0; i < 64; ++i) acc = fmaf(h[b][i], gw2[j * 64 + i], acc);
    g[b * 32 + j] = acc;
  }
}

// ---- pack conv weights bf16 [o][kt*CIN+c]; deform weights B-frag-packed ----
// cwpk: lw1p[32][576] @0, lw2p[32][288] @18432, fw1p[32][576] @27648,
//       fw2p[32][288] @46080 (rows>=18 zero).
// dwq:  [kt][cg][og][l15][l4][8] = bf16(dw[(og*16+l15)*64 + cg*32+l4*8+i][kt])
__global__ __launch_bounds__(256) void wprep_kernel(
    const float* __restrict__ lw1, const float* __restrict__ lw2,
    const float* __restrict__ fw1, const float* __restrict__ fw2,
    const float* __restrict__ dw, unsigned short* __restrict__ cwpk,
    unsigned short* __restrict__ dwq) {
  int i = blockIdx.x * 256 + threadIdx.x;
  if (i < 18432) {
    int o = i / 576, K = i - o * 576, kt = K >> 6, c = K & 63;
    cwpk[i] = f2bf(lw1[(o * 64 + c) * 9 + kt]);
  } else if (i < 27648) {
    int j = i - 18432;
    int o = j / 288, K = j - o * 288, kt = K >> 5, c = K & 31;
    cwpk[i] = f2bf(lw2[(o * 32 + c) * 9 + kt]);
  } else if (i < 46080) {
    int j = i - 27648;
    int o = j / 576, K = j - o * 576, kt = K >> 6, c = K & 63;
    cwpk[i] = f2bf(fw1[(o * 64 + c) * 9 + kt]);
  } else if (i < 55296) {
    int j = i - 46080;
    int o = j / 288, K = j - o * 288, kt = K >> 5, c = K & 31;
    cwpk[i] = (o < 18) ? f2bf(fw2[(o * 32 + c) * 9 + kt]) : (unsigned short)0;
  } else if (i < 55296 + 36864) {
    int j = i - 55296;
    int e = j & 7, l4 = (j >> 3) & 3, l15 = (j >> 5) & 15;
    int og = (j >> 9) & 3, cg = (j >> 11) & 1, kt = j >> 12;
    int o = og * 16 + l15, c = cg * 32 + l4 * 8 + e;
    dwq[j] = f2bf(dw[(o * 64 + c) * 9 + kt]);
  }
}

// ---- x -> channel-last bf16: xt[b][p][64] ----
__global__ __launch_bounds__(256) void xtprep_kernel(
    const float* __restrict__ x, unsigned short* __restrict__ xt) {
  int t = blockIdx.x * 256 + threadIdx.x;  // 8*16384 pixels
  int b = t >> 14, p = t & 16383;
  const float* xb = x + (size_t)b * 64 * HWSZ + p;
  unsigned short* ob = xt + (size_t)t * 64;
#pragma unroll
  for (int c0 = 0; c0 < 64; c0 += 8) {
    short8 v;
#pragma unroll
    for (int i = 0; i < 8; ++i) v[i] = (short)f2bf(xb[(size_t)(c0 + i) * HWSZ]);
    *(short8*)(ob + c0) = v;
  }
}

// ---------------- conv 3x3 via MFMA, implicit GEMM ----------------
template <int CINS, int NCG, bool GFUSE, bool RELU, bool CLOUT>
__global__ __launch_bounds__(256) void conv_mfma_kernel(
    const unsigned short* __restrict__ in, const unsigned short* __restrict__ wpk,
    const float* __restrict__ bias, const float* __restrict__ g,
    void* __restrict__ outv, int Cout) {
  constexpr int CIN = GFUSE ? 64 : NCG * 32;
  const int b = blockIdx.y, h = blockIdx.x;
  const int lane = threadIdx.x & 63, wave = threadIdx.x >> 6;
  const int l15 = lane & 15, l4 = lane >> 4;
  const unsigned short* inb = in + (size_t)b * HWSZ * CINS;
  const short8 zfr = {0, 0, 0, 0, 0, 0, 0, 0};
  short8 gfr = zfr;
  if (GFUSE) {
#pragma unroll
    for (int i = 0; i < 8; ++i) gfr[i] = (short)f2bf(g[b * 32 + l4 * 8 + i]);
  }
  f32x4 acc[2][2];
#pragma unroll
  for (int f = 0; f < 2; ++f)
#pragma unroll
    for (int j = 0; j < 2; ++j) acc[f][j] = (f32x4){0.f, 0.f, 0.f, 0.f};

  for (int kt = 0; kt < 9; ++kt) {
    const int ki = kt / 3 - 1, kj = kt % 3 - 1;
    const int y = h + ki;
    const bool yok = (unsigned)y < HH;
    const int yc = min(max(y, 0), HH - 1);
    int xs[2];
    bool ok[2];
#pragma unroll
    for (int j = 0; j < 2; ++j) {
      int xx = wave * 32 + j * 16 + l15 + kj;
      ok[j] = yok && ((unsigned)xx < WW);
      xs[j] = min(max(xx, 0), WW - 1);
    }
    const unsigned short* wr = wpk + kt * CIN + l4 * 8;
#pragma unroll
    for (int cg = 0; cg < NCG; ++cg) {
      short8 afr0 = *(const short8*)(wr + cg * 32 + (size_t)l15 * (9 * CIN));
      short8 afr1 = *(const short8*)(wr + cg * 32 + (size_t)(l15 + 16) * (9 * CIN));
#pragma unroll
      for (int j = 0; j < 2; ++j) {
        short8 bv;
        if (GFUSE && cg == 0) {
          bv = ok[j] ? gfr : zfr;
        } else {
          const int csrc = GFUSE ? 0 : cg * 32;
          short8 ld = *(const short8*)(inb + (size_t)(yc * WW + xs[j]) * CINS + csrc + l4 * 8);
          bv = ok[j] ? ld : zfr;
        }
        acc[0][j] = __builtin_amdgcn_mfma_f32_16x16x32_bf16(afr0, bv, acc[0][j], 0, 0, 0);
        acc[1][j] = __builtin_amdgcn_mfma_f32_16x16x32_bf16(afr1, bv, acc[1][j], 0, 0, 0);
      }
    }
  }
  if (CLOUT) {  // channel-last bf16, Cout==32
    unsigned short* ob = (unsigned short*)outv + (size_t)b * HWSZ * 32;
#pragma unroll
    for (int f = 0; f < 2; ++f)
#pragma unroll
      for (int j = 0; j < 2; ++j) {
        int p = h * WW + wave * 32 + j * 16 + l15;
        int o0 = f * 16 + l4 * 4;
        short4v st;
#pragma unroll
        for (int r = 0; r < 4; ++r) {
          float v = acc[f][j][r] + bias[o0 + r];
          if (RELU) v = fmaxf(v, 0.f);
          st[r] = (short)f2bf(v);
        }
        *(short4v*)(ob + (size_t)p * 32 + o0) = st;
      }
  } else {  // NCHW fp32
    float* ob = (float*)outv + (size_t)b * Cout * HWSZ;
#pragma unroll
    for (int f = 0; f < 2; ++f)
#pragma unroll
      for (int j = 0; j < 2; ++j) {
        int p = h * WW + wave * 32 + j * 16 + l15;
#pragma unroll
        for (int r = 0; r < 4; ++r) {
          int o = f * 16 + l4 * 4 + r;
          if (o < Cout) {
            float v = acc[f][j][r] + bias[o];
            if (RELU) v = fmaxf(v, 0.f);
            ob[(size_t)o * HWSZ + p] = v;
          }
        }
      }
  }
}

// ---------------- deformable conv via MFMA (operand-swapped) ----------------
// wave = 16 px x 64 outs. D[px][o] = samples[px][K] * w[K][o].
// A frag (samples): lane holds A[row=l15][k=l4*8+i] -> built in-reg.
// B frag (weights): lane holds B[k=l4*8+i][col=l15] -> coalesced from dwq.
// D: lane holds D[row=l4*4+r][col=l15] = out[pixel p0+l4*4+r][o=og*16+l15].
__global__ __launch_bounds__(256) void deform_mfma_kernel(
    const unsigned short* __restrict__ xt, const float* __restrict__ offset,
    const unsigned short* __restrict__ dwq, const float* __restrict__ db,
    float* __restrict__ out) {
  const int b = blockIdx.y;
  const int h = blockIdx.x >> 1;
  const int halfx = (blockIdx.x & 1) * 64;
  const int lane = threadIdx.x & 63, wave = threadIdx.x >> 6;
  const int l15 = lane & 15, l4 = lane >> 4;
  const int wx = halfx + wave * 16;      // wave's first x
  const int p0 = h * WW + wx;            // wave's first pixel
  const int myw = wx + l15;              // x-coord this lane samples for
  const int mypix = p0 + l15;
  const unsigned short* xb = xt + (size_t)b * HWSZ * 64;
  const float* offb = offset + (size_t)b * 18 * HWSZ;

  float off[18];
#pragma unroll
  for (int c = 0; c < 18; ++c) off[c] = offb[(size_t)c * HWSZ + mypix];

  f32x4 acc[4];
#pragma unroll
  for (int og = 0; og < 4; ++og) acc[og] = (f32x4){0.f, 0.f, 0.f, 0.f};

#pragma unroll
  for (int kt = 0; kt < 9; ++kt) {
    const int ki = kt / 3 - 1, kj = kt % 3 - 1;
    float py = (float)(h + ki) + off[2 * kt];
    float px = (float)(myw + kj) + off[2 * kt + 1];
    float y0f = floorf(py), x0f = floorf(px);
    float wy1 = py - y0f, wy0 = 1.f - wy1;
    float wx1 = px - x0f, wx0 = 1.f - wx1;
    int y0 = (int)y0f, x0i = (int)x0f;
    int y1 = y0 + 1, x1i = x0i + 1;
    bool y0ok = (unsigned)y0 < HH, y1ok = (unsigned)y1 < HH;
    bool x0ok = (unsigned)x0i < WW, x1ok = (unsigned)x1i < WW;
    float w00 = (y0ok && x0ok) ? wy0 * wx0 : 0.f;
    float w01 = (y0ok && x1ok) ? wy0 * wx1 : 0.f;
    float w10 = (y1ok && x0ok) ? wy1 * wx0 : 0.f;
    float w11 = (y1ok && x1ok) ? wy1 * wx1 : 0.f;
    int y0c = min(max(y0, 0), HH - 1), y1c = min(max(y1, 0), HH - 1);
    int x0c = min(max(x0i, 0), WW - 1), x1c = min(max(x1i, 0), WW - 1);
    int i00 = y0c * WW + x0c, i01 = y0c * WW + x1c;
    int i10 = y1c * WW + x0c, i11 = y1c * WW + x1c;
    const unsigned short* cbase = xb + l4 * 8;
#pragma unroll
    for (int cg = 0; cg < 2; ++cg) {
      const unsigned short* cb = cbase + cg * 32;
      short8 c00 = *(const short8*)(cb + (size_t)i00 * 64);
      short8 c01 = *(const short8*)(cb + (size_t)i01 * 64);
      short8 c10 = *(const short8*)(cb + (size_t)i10 * 64);
      short8 c11 = *(const short8*)(cb + (size_t)i11 * 64);
      short8 av;
#pragma unroll
      for (int i = 0; i < 8; ++i) {
        float s = w00 * bf2f(c00[i]) + w01 * bf2f(c01[i])
                + w10 * bf2f(c10[i]) + w11 * bf2f(c11[i]);
        av[i] = (short)f2bf(s);
      }
      const unsigned short* wq = dwq + ((size_t)(kt * 2 + cg) * 4 * 16 + l15) * 32 + l4 * 8;
#pragma unroll
      for (int og = 0; og < 4; ++og) {
        short8 bfr = *(const short8*)(wq + og * 512);
        acc[og] = __builtin_amdgcn_mfma_f32_16x16x32_bf16(av, bfr, acc[og], 0, 0, 0);
      }
    }
  }
  float* outb = out + (size_t)b * CC * HWSZ;
#pragma unroll
  for (int og = 0; og < 4; ++og) {
    int o = og * 16 + l15;
    float bv = db[o];
    f32x4 st;
#pragma unroll
    for (int r = 0; r < 4; ++r) st[r] = fmaxf(acc[og][r] + bv, 0.f);
    *(f32x4*)(outb + (size_t)o * HWSZ + p0 + l4 * 4) = st;
  }
}

extern "C" void kernel_launch(void* const* d_in, const int* in_sizes, int n_in,
                              void* d_out, int out_size, void* d_ws, size_t ws_size,
                              hipStream_t stream) {
  const float* x     = (const float*)d_in[0];
  const float* bsize = (const float*)d_in[1];
  const float* gw1   = (const float*)d_in[2];
  const float* gb1   = (const float*)d_in[3];
  const float* gw2   = (const float*)d_in[4];
  const float* gb2   = (const float*)d_in[5];
  const float* lw1   = (const float*)d_in[6];
  const float* lb1   = (const float*)d_in[7];
  const float* lw2   = (const float*)d_in[8];
  const float* lb2   = (const float*)d_in[9];
  const float* fw1   = (const float*)d_in[10];
  const float* fb1   = (const float*)d_in[11];
  const float* fw2   = (const float*)d_in[12];
  const float* fb2   = (const float*)d_in[13];
  const float* dw    = (const float*)d_in[14];
  const float* db    = (const float*)d_in[15];
  float* out = (float*)d_out;

  // ws layout: gbuf(2KB) | xt bf16 (16.8MB) | offset fp32 (9.4MB) | dwq (74KB)
  float* gbuf = (float*)d_ws;
  unsigned short* xt = (unsigned short*)((char*)d_ws + 2048);
  float* offset = (float*)((char*)d_ws + 2048 + (size_t)BB * HWSZ * 64 * 2);
  unsigned short* dwq = (unsigned short*)((char*)offset + (size_t)BB * 18 * HWSZ * 4);

  // d_out scratch: loff bf16 CL @0 | cwpk @8.39MB | t1/t2 bf16 CL @16.78MB
  unsigned short* loff = (unsigned short*)d_out;
  unsigned short* cwpk = (unsigned short*)d_out + 4194304;
  unsigned short* t12  = (unsigned short*)d_out + 8388608;
  const unsigned short* lw1p = cwpk;
  const unsigned short* lw2p = cwpk + 18432;
  const unsigned short* fw1p = cwpk + 27648;
  const unsigned short* fw2p = cwpk + 46080;

  g_mlp_kernel<<<1, 512, 0, stream>>>(bsize, gw1, gb1, gw2, gb2, gbuf);
  wprep_kernel<<<360, 256, 0, stream>>>(lw1, lw2, fw1, fw2, dw, cwpk, dwq);
  xtprep_kernel<<<512, 256, 0, stream>>>(x, xt);
  // t1 = relu(conv(x, lw1))
  conv_mfma_kernel<64, 2, false, true, true><<<dim3(128, 8), 256, 0, stream>>>(
      xt, lw1p, lb1, nullptr, t12, 32);
  // loff = conv(t1, lw2)
  conv_mfma_kernel<32, 1, false, false, true><<<dim3(128, 8), 256, 0, stream>>>(
      t12, lw2p, lb2, nullptr, loff, 32);
  // t2 = relu(conv(concat(g, loff), fw1))
  conv_mfma_kernel<32, 2, true, true, true><<<dim3(128, 8), 256, 0, stream>>>(
      loff, fw1p, fb1, gbuf, t12, 32);
  // offset = conv(t2, fw2), Cout=18, NCHW fp32
  conv_mfma_kernel<32, 1, false, false, false><<<dim3(128, 8), 256, 0, stream>>>(
      t12, fw2p, fb2, nullptr, offset, 18);
  // out = relu(deform_conv(x, offset, dw) + db)
  deform_mfma_kernel<<<dim3(256, 8), 256, 0, stream>>>(xt, offset, dwq, db, out);
}

// Round 5
// 202.245 us; speedup vs baseline: 5.9368x; 1.0076x over previous
//
#include <hip/hip_runtime.h>

#define BB 8
#define CC 64
#define HH 128
#define WW 128
#define HWSZ (HH*WW)

typedef _Float16 h16;
typedef __attribute__((ext_vector_type(8))) _Float16 h16x8;
typedef __attribute__((ext_vector_type(4))) _Float16 h16x4;
typedef __attribute__((ext_vector_type(2))) _Float16 h16x2;
typedef __attribute__((ext_vector_type(4))) float f32x4;

// ---------------- g MLP ----------------
__global__ __launch_bounds__(512) void g_mlp_kernel(
    const float* __restrict__ bsize, const float* __restrict__ gw1,
    const float* __restrict__ gb1, const float* __restrict__ gw2,
    const float* __restrict__ gb2, float* __restrict__ g) {
  __shared__ float h[BB][64];
  int t = threadIdx.x;
  if (t < BB * 64) {
    int b = t >> 6, i = t & 63;
    float v = fmaf(bsize[b * 2 + 0], gw1[i * 2 + 0],
                   fmaf(bsize[b * 2 + 1], gw1[i * 2 + 1], gb1[i]));
    h[b][i] = fmaxf(v, 0.f);
  }
  __syncthreads();
  if (t < BB * 32) {
    int b = t >> 5, j = t & 31;
    float acc = gb2[j];
#pragma unroll
    for (int i = 0; i < 64; ++i) acc = fmaf(h[b][i], gw2[j * 64 + i], acc);
    g[b * 32 + j] = acc;
  }
}

// ---- pack conv weights f16 [o][kt*CIN+c]; deform weights B-frag-packed ----
__global__ __launch_bounds__(256) void wprep_kernel(
    const float* __restrict__ lw1, const float* __restrict__ lw2,
    const float* __restrict__ fw1, const float* __restrict__ fw2,
    const float* __restrict__ dw, h16* __restrict__ cwpk,
    h16* __restrict__ dwq) {
  int i = blockIdx.x * 256 + threadIdx.x;
  if (i < 18432) {
    int o = i / 576, K = i - o * 576, kt = K >> 6, c = K & 63;
    cwpk[i] = (h16)lw1[(o * 64 + c) * 9 + kt];
  } else if (i < 27648) {
    int j = i - 18432;
    int o = j / 288, K = j - o * 288, kt = K >> 5, c = K & 31;
    cwpk[i] = (h16)lw2[(o * 32 + c) * 9 + kt];
  } else if (i < 46080) {
    int j = i - 27648;
    int o = j / 576, K = j - o * 576, kt = K >> 6, c = K & 63;
    cwpk[i] = (h16)fw1[(o * 64 + c) * 9 + kt];
  } else if (i < 55296) {
    int j = i - 46080;
    int o = j / 288, K = j - o * 288, kt = K >> 5, c = K & 31;
    cwpk[i] = (o < 18) ? (h16)fw2[(o * 32 + c) * 9 + kt] : (h16)0.f;
  } else if (i < 55296 + 36864) {
    int j = i - 55296;
    int e = j & 7, l4 = (j >> 3) & 3, l15 = (j >> 5) & 15;
    int og = (j >> 9) & 3, cg = (j >> 11) & 1, kt = j >> 12;
    int o = og * 16 + l15, c = cg * 32 + l4 * 8 + e;
    dwq[j] = (h16)dw[(o * 64 + c) * 9 + kt];
  }
}

// ---- x -> channel-last f16: xt[b][p][64] ----
__global__ __launch_bounds__(256) void xtprep_kernel(
    const float* __restrict__ x, h16* __restrict__ xt) {
  int t = blockIdx.x * 256 + threadIdx.x;
  int b = t >> 14, p = t & 16383;
  const float* xb = x + (size_t)b * 64 * HWSZ + p;
  h16* ob = xt + (size_t)t * 64;
#pragma unroll
  for (int c0 = 0; c0 < 64; c0 += 8) {
    h16x8 v;
#pragma unroll
    for (int i = 0; i < 8; ++i) v[i] = (h16)xb[(size_t)(c0 + i) * HWSZ];
    *(h16x8*)(ob + c0) = v;
  }
}

// ---------------- conv 3x3 via MFMA, implicit GEMM (f16) ----------------
// OMODE 0: channel-last f16 stride 32 (Cout=32).
// OMODE 1: offsets channel-last f16 stride 24 (Cout=18).
template <int CINS, int NCG, bool GFUSE, bool RELU, int OMODE>
__global__ __launch_bounds__(256) void conv_mfma_kernel(
    const h16* __restrict__ in, const h16* __restrict__ wpk,
    const float* __restrict__ bias, const float* __restrict__ g,
    h16* __restrict__ outv) {
  constexpr int CIN = GFUSE ? 64 : NCG * 32;
  const int b = blockIdx.y, h = blockIdx.x;
  const int lane = threadIdx.x & 63, wave = threadIdx.x >> 6;
  const int l15 = lane & 15, l4 = lane >> 4;
  const h16* inb = in + (size_t)b * HWSZ * CINS;
  const h16x8 zfr = {0, 0, 0, 0, 0, 0, 0, 0};
  h16x8 gfr = zfr;
  if (GFUSE) {
#pragma unroll
    for (int i = 0; i < 8; ++i) gfr[i] = (h16)g[b * 32 + l4 * 8 + i];
  }
  f32x4 acc[2][2];
#pragma unroll
  for (int f = 0; f < 2; ++f)
#pragma unroll
    for (int j = 0; j < 2; ++j) acc[f][j] = (f32x4){0.f, 0.f, 0.f, 0.f};

  for (int kt = 0; kt < 9; ++kt) {
    const int ki = kt / 3 - 1, kj = kt % 3 - 1;
    const int y = h + ki;
    const bool yok = (unsigned)y < HH;
    const int yc = min(max(y, 0), HH - 1);
    int xs[2];
    bool ok[2];
#pragma unroll
    for (int j = 0; j < 2; ++j) {
      int xx = wave * 32 + j * 16 + l15 + kj;
      ok[j] = yok && ((unsigned)xx < WW);
      xs[j] = min(max(xx, 0), WW - 1);
    }
    const h16* wr = wpk + kt * CIN + l4 * 8;
#pragma unroll
    for (int cg = 0; cg < NCG; ++cg) {
      h16x8 afr0 = *(const h16x8*)(wr + cg * 32 + (size_t)l15 * (9 * CIN));
      h16x8 afr1 = *(const h16x8*)(wr + cg * 32 + (size_t)(l15 + 16) * (9 * CIN));
#pragma unroll
      for (int j = 0; j < 2; ++j) {
        h16x8 bv;
        if (GFUSE && cg == 0) {
          bv = ok[j] ? gfr : zfr;
        } else {
          const int csrc = GFUSE ? 0 : cg * 32;
          h16x8 ld = *(const h16x8*)(inb + (size_t)(yc * WW + xs[j]) * CINS + csrc + l4 * 8);
          bv = ok[j] ? ld : zfr;
        }
        acc[0][j] = __builtin_amdgcn_mfma_f32_16x16x32_f16(afr0, bv, acc[0][j], 0, 0, 0);
        acc[1][j] = __builtin_amdgcn_mfma_f32_16x16x32_f16(afr1, bv, acc[1][j], 0, 0, 0);
      }
    }
  }
  if (OMODE == 0) {
    h16* ob = outv + (size_t)b * HWSZ * 32;
#pragma unroll
    for (int f = 0; f < 2; ++f)
#pragma unroll
      for (int j = 0; j < 2; ++j) {
        int p = h * WW + wave * 32 + j * 16 + l15;
        int o0 = f * 16 + l4 * 4;
        h16x4 st;
#pragma unroll
        for (int r = 0; r < 4; ++r) {
          float v = acc[f][j][r] + bias[o0 + r];
          if (RELU) v = fmaxf(v, 0.f);
          st[r] = (h16)v;
        }
        *(h16x4*)(ob + (size_t)p * 32 + o0) = st;
      }
  } else {
    h16* ob = outv + (size_t)b * HWSZ * 24;
#pragma unroll
    for (int j = 0; j < 2; ++j) {
      int p = h * WW + wave * 32 + j * 16 + l15;
      // f = 0: outputs l4*4 .. l4*4+3
      {
        int o0 = l4 * 4;
        h16x4 st;
#pragma unroll
        for (int r = 0; r < 4; ++r) st[r] = (h16)(acc[0][j][r] + bias[o0 + r]);
        *(h16x4*)(ob + (size_t)p * 24 + o0) = st;
      }
      // f = 1: only o=16,17 (l4==0, r=0,1)
      if (l4 == 0) {
        h16x2 st2;
        st2[0] = (h16)(acc[1][j][0] + bias[16]);
        st2[1] = (h16)(acc[1][j][1] + bias[17]);
        *(h16x2*)(ob + (size_t)p * 24 + 16) = st2;
      }
    }
  }
}

// ---------------- deformable conv via MFMA, 2-stage tap pipeline ----------------
// wave = 16 px x 64 outs. D[px][o] = samples[px][K] * w[K][o].
__global__ __launch_bounds__(256) void deform_mfma_kernel(
    const h16* __restrict__ xt, const h16* __restrict__ offc,
    const h16* __restrict__ dwq, const float* __restrict__ db,
    float* __restrict__ out) {
  const int b = blockIdx.y;
  const int h = blockIdx.x >> 1;
  const int halfx = (blockIdx.x & 1) * 64;
  const int lane = threadIdx.x & 63, wave = threadIdx.x >> 6;
  const int l15 = lane & 15, l4 = lane >> 4;
  const int wx = halfx + wave * 16;
  const int p0 = h * WW + wx;
  const int myw = wx + l15;
  const int mypix = p0 + l15;
  const h16* xb = xt + (size_t)b * HWSZ * 64;

  const h16* offp = offc + ((size_t)b * HWSZ + mypix) * 24;
  h16x8 offv0 = *(const h16x8*)(offp);
  h16x8 offv1 = *(const h16x8*)(offp + 8);
  h16x8 offv2 = *(const h16x8*)(offp + 16);

#define OFFE(e) ((e) < 8 ? (float)offv0[(e) & 7] : (e) < 16 ? (float)offv1[(e) & 7] : (float)offv2[(e) & 7])

  f32x4 acc[4];
#pragma unroll
  for (int og = 0; og < 4; ++og) acc[og] = (f32x4){0.f, 0.f, 0.f, 0.f};

  h16x8 cbf[2][2][4];  // [parity][cg][corner]
  h16 wb[2][4];        // [parity][corner]

#define TAP_ADDR_ISSUE(kt, par) do {                                        \
    const int ki_ = (kt) / 3 - 1, kj_ = (kt) % 3 - 1;                       \
    float py = (float)(h + ki_) + OFFE(2 * (kt));                           \
    float px = (float)(myw + kj_) + OFFE(2 * (kt) + 1);                     \
    float y0f = floorf(py), x0f = floorf(px);                               \
    float wy1 = py - y0f, wy0 = 1.f - wy1;                                  \
    float wx1 = px - x0f, wx0 = 1.f - wx1;                                  \
    int y0 = (int)y0f, x0i = (int)x0f;                                      \
    int y1 = y0 + 1, x1i = x0i + 1;                                         \
    bool y0ok = (unsigned)y0 < HH, y1ok = (unsigned)y1 < HH;                \
    bool x0ok = (unsigned)x0i < WW, x1ok = (unsigned)x1i < WW;              \
    wb[par][0] = (h16)((y0ok && x0ok) ? wy0 * wx0 : 0.f);                   \
    wb[par][1] = (h16)((y0ok && x1ok) ? wy0 * wx1 : 0.f);                   \
    wb[par][2] = (h16)((y1ok && x0ok) ? wy1 * wx0 : 0.f);                   \
    wb[par][3] = (h16)((y1ok && x1ok) ? wy1 * wx1 : 0.f);                   \
    int y0c = min(max(y0, 0), HH - 1), y1c = min(max(y1, 0), HH - 1);       \
    int x0c = min(max(x0i, 0), WW - 1), x1c = min(max(x1i, 0), WW - 1);     \
    int i00 = y0c * WW + x0c, i01 = y0c * WW + x1c;                         \
    int i10 = y1c * WW + x0c, i11 = y1c * WW + x1c;                         \
    const h16* cb0 = xb + l4 * 8;                                           \
    cbf[par][0][0] = *(const h16x8*)(cb0 + (size_t)i00 * 64);               \
    cbf[par][0][1] = *(const h16x8*)(cb0 + (size_t)i01 * 64);               \
    cbf[par][0][2] = *(const h16x8*)(cb0 + (size_t)i10 * 64);               \
    cbf[par][0][3] = *(const h16x8*)(cb0 + (size_t)i11 * 64);               \
    const h16* cb1 = cb0 + 32;                                              \
    cbf[par][1][0] = *(const h16x8*)(cb1 + (size_t)i00 * 64);               \
    cbf[par][1][1] = *(const h16x8*)(cb1 + (size_t)i01 * 64);               \
    cbf[par][1][2] = *(const h16x8*)(cb1 + (size_t)i10 * 64);               \
    cbf[par][1][3] = *(const h16x8*)(cb1 + (size_t)i11 * 64);               \
  } while (0)

#define TAP_CONSUME(kt, par) do {                                           \
    h16 w00 = wb[par][0], w01 = wb[par][1], w10 = wb[par][2], w11 = wb[par][3]; \
    h16x8 s0 = cbf[par][0][0] * w00 + cbf[par][0][1] * w01                  \
             + cbf[par][0][2] * w10 + cbf[par][0][3] * w11;                 \
    h16x8 s1 = cbf[par][1][0] * w00 + cbf[par][1][1] * w01                  \
             + cbf[par][1][2] * w10 + cbf[par][1][3] * w11;                 \
    const h16* wq0 = dwq + ((size_t)((kt) * 2 + 0) * 64 + l15) * 32 + l4 * 8; \
    const h16* wq1 = dwq + ((size_t)((kt) * 2 + 1) * 64 + l15) * 32 + l4 * 8; \
    acc[0] = __builtin_amdgcn_mfma_f32_16x16x32_f16(s0, *(const h16x8*)(wq0 + 0 * 512), acc[0], 0, 0, 0); \
    acc[1] = __builtin_amdgcn_mfma_f32_16x16x32_f16(s0, *(const h16x8*)(wq0 + 1 * 512), acc[1], 0, 0, 0); \
    acc[2] = __builtin_amdgcn_mfma_f32_16x16x32_f16(s0, *(const h16x8*)(wq0 + 2 * 512), acc[2], 0, 0, 0); \
    acc[3] = __builtin_amdgcn_mfma_f32_16x16x32_f16(s0, *(const h16x8*)(wq0 + 3 * 512), acc[3], 0, 0, 0); \
    acc[0] = __builtin_amdgcn_mfma_f32_16x16x32_f16(s1, *(const h16x8*)(wq1 + 0 * 512), acc[0], 0, 0, 0); \
    acc[1] = __builtin_amdgcn_mfma_f32_16x16x32_f16(s1, *(const h16x8*)(wq1 + 1 * 512), acc[1], 0, 0, 0); \
    acc[2] = __builtin_amdgcn_mfma_f32_16x16x32_f16(s1, *(const h16x8*)(wq1 + 2 * 512), acc[2], 0, 0, 0); \
    acc[3] = __builtin_amdgcn_mfma_f32_16x16x32_f16(s1, *(const h16x8*)(wq1 + 3 * 512), acc[3], 0, 0, 0); \
  } while (0)

  TAP_ADDR_ISSUE(0, 0);
  TAP_ADDR_ISSUE(1, 1);
  TAP_CONSUME(0, 0);
  TAP_ADDR_ISSUE(2, 0);
  TAP_CONSUME(1, 1);
  TAP_ADDR_ISSUE(3, 1);
  TAP_CONSUME(2, 0);
  TAP_ADDR_ISSUE(4, 0);
  TAP_CONSUME(3, 1);
  TAP_ADDR_ISSUE(5, 1);
  TAP_CONSUME(4, 0);
  TAP_ADDR_ISSUE(6, 0);
  TAP_CONSUME(5, 1);
  TAP_ADDR_ISSUE(7, 1);
  TAP_CONSUME(6, 0);
  TAP_ADDR_ISSUE(8, 0);
  TAP_CONSUME(7, 1);
  TAP_CONSUME(8, 0);

  float* outb = out + (size_t)b * CC * HWSZ;
#pragma unroll
  for (int og = 0; og < 4; ++og) {
    int o = og * 16 + l15;
    float bv = db[o];
    f32x4 st;
#pragma unroll
    for (int r = 0; r < 4; ++r) st[r] = fmaxf(acc[og][r] + bv, 0.f);
    *(f32x4*)(outb + (size_t)o * HWSZ + p0 + l4 * 4) = st;
  }
#undef TAP_ADDR_ISSUE
#undef TAP_CONSUME
#undef OFFE
}

extern "C" void kernel_launch(void* const* d_in, const int* in_sizes, int n_in,
                              void* d_out, int out_size, void* d_ws, size_t ws_size,
                              hipStream_t stream) {
  const float* x     = (const float*)d_in[0];
  const float* bsize = (const float*)d_in[1];
  const float* gw1   = (const float*)d_in[2];
  const float* gb1   = (const float*)d_in[3];
  const float* gw2   = (const float*)d_in[4];
  const float* gb2   = (const float*)d_in[5];
  const float* lw1   = (const float*)d_in[6];
  const float* lb1   = (const float*)d_in[7];
  const float* lw2   = (const float*)d_in[8];
  const float* lb2   = (const float*)d_in[9];
  const float* fw1   = (const float*)d_in[10];
  const float* fb1   = (const float*)d_in[11];
  const float* fw2   = (const float*)d_in[12];
  const float* fb2   = (const float*)d_in[13];
  const float* dw    = (const float*)d_in[14];
  const float* db    = (const float*)d_in[15];
  float* out = (float*)d_out;

  // ws layout: gbuf(2KB) | xt f16 16.78MB | offc f16 [b][p][24] 6.29MB | dwq 72KB
  float* gbuf = (float*)d_ws;
  h16* xt   = (h16*)((char*)d_ws + 2048);
  h16* offc = (h16*)((char*)d_ws + 2048 + (size_t)BB * HWSZ * 64 * 2);
  h16* dwq  = (h16*)((char*)offc + (size_t)BB * HWSZ * 24 * 2);

  // d_out scratch: loff f16 CL @0 | cwpk @8.39MB | t1/t2 f16 CL @16.78MB
  h16* loff = (h16*)d_out;
  h16* cwpk = (h16*)d_out + 4194304;
  h16* t12  = (h16*)d_out + 8388608;
  const h16* lw1p = cwpk;
  const h16* lw2p = cwpk + 18432;
  const h16* fw1p = cwpk + 27648;
  const h16* fw2p = cwpk + 46080;

  g_mlp_kernel<<<1, 512, 0, stream>>>(bsize, gw1, gb1, gw2, gb2, gbuf);
  wprep_kernel<<<360, 256, 0, stream>>>(lw1, lw2, fw1, fw2, dw, cwpk, dwq);
  xtprep_kernel<<<512, 256, 0, stream>>>(x, xt);
  // t1 = relu(conv(x, lw1))
  conv_mfma_kernel<64, 2, false, true, 0><<<dim3(128, 8), 256, 0, stream>>>(
      xt, lw1p, lb1, nullptr, t12);
  // loff = conv(t1, lw2)
  conv_mfma_kernel<32, 1, false, false, 0><<<dim3(128, 8), 256, 0, stream>>>(
      t12, lw2p, lb2, nullptr, loff);
  // t2 = relu(conv(concat(g, loff), fw1))
  conv_mfma_kernel<32, 2, true, true, 0><<<dim3(128, 8), 256, 0, stream>>>(
      loff, fw1p, fb1, gbuf, t12);
  // offc = conv(t2, fw2), Cout=18, channel-last f16 stride 24
  conv_mfma_kernel<32, 1, false, false, 1><<<dim3(128, 8), 256, 0, stream>>>(
      t12, fw2p, fb2, nullptr, offc);
  // out = relu(deform_conv(x, offset, dw) + db)
  deform_mfma_kernel<<<dim3(256, 8), 256, 0, stream>>>(xt, offc, dwq, db, out);
}

// Round 6
// 159.155 us; speedup vs baseline: 7.5441x; 1.2707x over previous
//
#include <hip/hip_runtime.h>

#define BB 8
#define CC 64
#define HH 128
#define WW 128
#define HWSZ (HH*WW)

typedef _Float16 h16;
typedef __attribute__((ext_vector_type(8))) _Float16 h16x8;
typedef __attribute__((ext_vector_type(4))) _Float16 h16x4;
typedef __attribute__((ext_vector_type(2))) _Float16 h16x2;
typedef __attribute__((ext_vector_type(4))) float f32x4;

// ---------------- g MLP ----------------
__global__ __launch_bounds__(512) void g_mlp_kernel(
    const float* __restrict__ bsize, const float* __restrict__ gw1,
    const float* __restrict__ gb1, const float* __restrict__ gw2,
    const float* __restrict__ gb2, float* __restrict__ g) {
  __shared__ float h[BB][64];
  int t = threadIdx.x;
  if (t < BB * 64) {
    int b = t >> 6, i = t & 63;
    float v = fmaf(bsize[b * 2 + 0], gw1[i * 2 + 0],
                   fmaf(bsize[b * 2 + 1], gw1[i * 2 + 1], gb1[i]));
    h[b][i] = fmaxf(v, 0.f);
  }
  __syncthreads();
  if (t < BB * 32) {
    int b = t >> 5, j = t & 31;
    float acc = gb2[j];
#pragma unroll
    for (int i = 0; i < 64; ++i) acc = fmaf(h[b][i], gw2[j * 64 + i], acc);
    g[b * 32 + j] = acc;
  }
}

// ---- pack conv weights f16 [o][kt*CIN+c]; deform weights B-frag-packed ----
__global__ __launch_bounds__(256) void wprep_kernel(
    const float* __restrict__ lw1, const float* __restrict__ lw2,
    const float* __restrict__ fw1, const float* __restrict__ fw2,
    const float* __restrict__ dw, h16* __restrict__ cwpk,
    h16* __restrict__ dwq) {
  int i = blockIdx.x * 256 + threadIdx.x;
  if (i < 18432) {
    int o = i / 576, K = i - o * 576, kt = K >> 6, c = K & 63;
    cwpk[i] = (h16)lw1[(o * 64 + c) * 9 + kt];
  } else if (i < 27648) {
    int j = i - 18432;
    int o = j / 288, K = j - o * 288, kt = K >> 5, c = K & 31;
    cwpk[i] = (h16)lw2[(o * 32 + c) * 9 + kt];
  } else if (i < 46080) {
    int j = i - 27648;
    int o = j / 576, K = j - o * 576, kt = K >> 6, c = K & 63;
    cwpk[i] = (h16)fw1[(o * 64 + c) * 9 + kt];
  } else if (i < 55296) {
    int j = i - 46080;
    int o = j / 288, K = j - o * 288, kt = K >> 5, c = K & 31;
    cwpk[i] = (o < 18) ? (h16)fw2[(o * 32 + c) * 9 + kt] : (h16)0.f;
  } else if (i < 55296 + 36864) {
    int j = i - 55296;
    int e = j & 7, l4 = (j >> 3) & 3, l15 = (j >> 5) & 15;
    int og = (j >> 9) & 3, cg = (j >> 11) & 1, kt = j >> 12;
    int o = og * 16 + l15, c = cg * 32 + l4 * 8 + e;
    dwq[j] = (h16)dw[(o * 64 + c) * 9 + kt];
  }
}

// ---- x -> channel-last f16: xt[b][p][64] ----
__global__ __launch_bounds__(256) void xtprep_kernel(
    const float* __restrict__ x, h16* __restrict__ xt) {
  int t = blockIdx.x * 256 + threadIdx.x;
  int b = t >> 14, p = t & 16383;
  const float* xb = x + (size_t)b * 64 * HWSZ + p;
  h16* ob = xt + (size_t)t * 64;
#pragma unroll
  for (int c0 = 0; c0 < 64; c0 += 8) {
    h16x8 v;
#pragma unroll
    for (int i = 0; i < 8; ++i) v[i] = (h16)xb[(size_t)(c0 + i) * HWSZ];
    *(h16x8*)(ob + c0) = v;
  }
}

// ---------------- conv 3x3 via MFMA, implicit GEMM (f16) ----------------
template <int CINS, int NCG, bool GFUSE, bool RELU, int OMODE>
__global__ __launch_bounds__(256) void conv_mfma_kernel(
    const h16* __restrict__ in, const h16* __restrict__ wpk,
    const float* __restrict__ bias, const float* __restrict__ g,
    h16* __restrict__ outv) {
  constexpr int CIN = GFUSE ? 64 : NCG * 32;
  const int b = blockIdx.y, h = blockIdx.x;
  const int lane = threadIdx.x & 63, wave = threadIdx.x >> 6;
  const int l15 = lane & 15, l4 = lane >> 4;
  const h16* inb = in + (size_t)b * HWSZ * CINS;
  const h16x8 zfr = {0, 0, 0, 0, 0, 0, 0, 0};
  h16x8 gfr = zfr;
  if (GFUSE) {
#pragma unroll
    for (int i = 0; i < 8; ++i) gfr[i] = (h16)g[b * 32 + l4 * 8 + i];
  }
  f32x4 acc[2][2];
#pragma unroll
  for (int f = 0; f < 2; ++f)
#pragma unroll
    for (int j = 0; j < 2; ++j) acc[f][j] = (f32x4){0.f, 0.f, 0.f, 0.f};

  for (int kt = 0; kt < 9; ++kt) {
    const int ki = kt / 3 - 1, kj = kt % 3 - 1;
    const int y = h + ki;
    const bool yok = (unsigned)y < HH;
    const int yc = min(max(y, 0), HH - 1);
    int xs[2];
    bool ok[2];
#pragma unroll
    for (int j = 0; j < 2; ++j) {
      int xx = wave * 32 + j * 16 + l15 + kj;
      ok[j] = yok && ((unsigned)xx < WW);
      xs[j] = min(max(xx, 0), WW - 1);
    }
    const h16* wr = wpk + kt * CIN + l4 * 8;
#pragma unroll
    for (int cg = 0; cg < NCG; ++cg) {
      h16x8 afr0 = *(const h16x8*)(wr + cg * 32 + (size_t)l15 * (9 * CIN));
      h16x8 afr1 = *(const h16x8*)(wr + cg * 32 + (size_t)(l15 + 16) * (9 * CIN));
#pragma unroll
      for (int j = 0; j < 2; ++j) {
        h16x8 bv;
        if (GFUSE && cg == 0) {
          bv = ok[j] ? gfr : zfr;
        } else {
          const int csrc = GFUSE ? 0 : cg * 32;
          h16x8 ld = *(const h16x8*)(inb + (size_t)(yc * WW + xs[j]) * CINS + csrc + l4 * 8);
          bv = ok[j] ? ld : zfr;
        }
        acc[0][j] = __builtin_amdgcn_mfma_f32_16x16x32_f16(afr0, bv, acc[0][j], 0, 0, 0);
        acc[1][j] = __builtin_amdgcn_mfma_f32_16x16x32_f16(afr1, bv, acc[1][j], 0, 0, 0);
      }
    }
  }
  if (OMODE == 0) {
    h16* ob = outv + (size_t)b * HWSZ * 32;
#pragma unroll
    for (int f = 0; f < 2; ++f)
#pragma unroll
      for (int j = 0; j < 2; ++j) {
        int p = h * WW + wave * 32 + j * 16 + l15;
        int o0 = f * 16 + l4 * 4;
        h16x4 st;
#pragma unroll
        for (int r = 0; r < 4; ++r) {
          float v = acc[f][j][r] + bias[o0 + r];
          if (RELU) v = fmaxf(v, 0.f);
          st[r] = (h16)v;
        }
        *(h16x4*)(ob + (size_t)p * 32 + o0) = st;
      }
  } else {
    h16* ob = outv + (size_t)b * HWSZ * 24;
#pragma unroll
    for (int j = 0; j < 2; ++j) {
      int p = h * WW + wave * 32 + j * 16 + l15;
      {
        int o0 = l4 * 4;
        h16x4 st;
#pragma unroll
        for (int r = 0; r < 4; ++r) st[r] = (h16)(acc[0][j][r] + bias[o0 + r]);
        *(h16x4*)(ob + (size_t)p * 24 + o0) = st;
      }
      if (l4 == 0) {
        h16x2 st2;
        st2[0] = (h16)(acc[1][j][0] + bias[16]);
        st2[1] = (h16)(acc[1][j][1] + bias[17]);
        *(h16x2*)(ob + (size_t)p * 24 + 16) = st2;
      }
    }
  }
}

// ---------------- deformable conv via MFMA + LDS x-tile ----------------
// block = 4 waves = (b, row h, 64-px half). wave = 16 px x 64 outs.
// LDS tile: rows h-2..h+2 (5), cols x_lo..x_lo+71 (72), 64 ch. 46KB.
// slot swizzle: physical slot = (cg*4+l4) ^ (tx&7)  (slot = 16B of 8 ch).
// Fallback to global gather when a corner falls outside the tile.
__global__ __launch_bounds__(256) void deform_mfma_kernel(
    const h16* __restrict__ xt, const h16* __restrict__ offc,
    const h16* __restrict__ dwq, const float* __restrict__ db,
    float* __restrict__ out) {
  __shared__ __align__(16) h16 sh[5 * 72 * 64];
  const int b = blockIdx.y;
  const int h = blockIdx.x >> 1;
  const int halfx = (blockIdx.x & 1) * 64;
  const int x_lo = halfx - 4;
  const int lane = threadIdx.x & 63, wave = threadIdx.x >> 6;
  const int l15 = lane & 15, l4 = lane >> 4;
  const int wx = halfx + wave * 16;
  const int p0 = h * WW + wx;
  const int myw = wx + l15;
  const int mypix = p0 + l15;
  const h16* xb = xt + (size_t)b * HWSZ * 64;

  // ---- stage tile (coalesced, swizzled) ----
#pragma unroll
  for (int it = 0; it < 12; ++it) {
    int q = it * 256 + threadIdx.x;  // 16B-chunk index
    if (q < 2880) {
      int s = q & 7, pr = q >> 3;
      int r = pr / 72, i = pr - r * 72;
      int gy = min(max(h - 2 + r, 0), HH - 1);
      int gx = min(max(x_lo + i, 0), WW - 1);
      h16x8 v = *(const h16x8*)(xb + ((size_t)gy * WW + gx) * 64 + s * 8);
      *(h16x8*)(sh + pr * 64 + ((s ^ (i & 7)) * 8)) = v;
    }
  }

  const h16* offp = offc + ((size_t)b * HWSZ + mypix) * 24;
  h16x8 offv0 = *(const h16x8*)(offp);
  h16x8 offv1 = *(const h16x8*)(offp + 8);
  h16x8 offv2 = *(const h16x8*)(offp + 16);
  __syncthreads();

#define OFFE(e) ((e) < 8 ? (float)offv0[(e) & 7] : (e) < 16 ? (float)offv1[(e) & 7] : (float)offv2[(e) & 7])

  f32x4 acc[4];
#pragma unroll
  for (int og = 0; og < 4; ++og) acc[og] = (f32x4){0.f, 0.f, 0.f, 0.f};

#pragma unroll
  for (int kt = 0; kt < 9; ++kt) {
    const int ki = kt / 3 - 1, kj = kt % 3 - 1;
    float py = (float)(h + ki) + OFFE(2 * kt);
    float px = (float)(myw + kj) + OFFE(2 * kt + 1);
    float y0f = floorf(py), x0f = floorf(px);
    float wy1 = py - y0f, wy0 = 1.f - wy1;
    float wx1 = px - x0f, wx0 = 1.f - wx1;
    int y0 = (int)y0f, x0i = (int)x0f;
    int y1 = y0 + 1, x1i = x0i + 1;
    bool y0ok = (unsigned)y0 < HH, y1ok = (unsigned)y1 < HH;
    bool x0ok = (unsigned)x0i < WW, x1ok = (unsigned)x1i < WW;
    h16 w00 = (h16)((y0ok && x0ok) ? wy0 * wx0 : 0.f);
    h16 w01 = (h16)((y0ok && x1ok) ? wy0 * wx1 : 0.f);
    h16 w10 = (h16)((y1ok && x0ok) ? wy1 * wx0 : 0.f);
    h16 w11 = (h16)((y1ok && x1ok) ? wy1 * wx1 : 0.f);
    int y0c = min(max(y0, 0), HH - 1), y1c = min(max(y1, 0), HH - 1);
    int x0c = min(max(x0i, 0), WW - 1), x1c = min(max(x1i, 0), WW - 1);
    // tile coords
    int ty0u = y0c - (h - 2), ty1u = y1c - (h - 2);
    int tx0u = x0c - x_lo, tx1u = x1c - x_lo;
    bool fast = ((unsigned)ty0u <= 4u) & ((unsigned)ty1u <= 4u) &
                ((unsigned)tx0u <= 71u) & ((unsigned)tx1u <= 71u);
    int ty0 = min(max(ty0u, 0), 4), ty1 = min(max(ty1u, 0), 4);
    int tx0 = min(max(tx0u, 0), 71), tx1 = min(max(tx1u, 0), 71);
    int pr00 = (ty0 * 72 + tx0) * 64, pr01 = (ty0 * 72 + tx1) * 64;
    int pr10 = (ty1 * 72 + tx0) * 64, pr11 = (ty1 * 72 + tx1) * 64;
    int sx0 = (tx0 & 7) * 8, sx1 = (tx1 & 7) * 8;
    h16x8 c00[2], c01[2], c10[2], c11[2];
#pragma unroll
    for (int cg = 0; cg < 2; ++cg) {
      int sb = (cg * 4 + l4) * 8;
      c00[cg] = *(const h16x8*)(sh + pr00 + (sb ^ sx0));
      c01[cg] = *(const h16x8*)(sh + pr01 + (sb ^ sx1));
      c10[cg] = *(const h16x8*)(sh + pr10 + (sb ^ sx0));
      c11[cg] = *(const h16x8*)(sh + pr11 + (sb ^ sx1));
    }
    if (!fast) {  // rare: large offsets — exact global gather
      int i00 = y0c * WW + x0c, i01 = y0c * WW + x1c;
      int i10 = y1c * WW + x0c, i11 = y1c * WW + x1c;
#pragma unroll
      for (int cg = 0; cg < 2; ++cg) {
        const h16* cb = xb + cg * 32 + l4 * 8;
        c00[cg] = *(const h16x8*)(cb + (size_t)i00 * 64);
        c01[cg] = *(const h16x8*)(cb + (size_t)i01 * 64);
        c10[cg] = *(const h16x8*)(cb + (size_t)i10 * 64);
        c11[cg] = *(const h16x8*)(cb + (size_t)i11 * 64);
      }
    }
    const h16* wq0 = dwq + ((size_t)(kt * 2 + 0) * 64 + l15) * 32 + l4 * 8;
    const h16* wq1 = dwq + ((size_t)(kt * 2 + 1) * 64 + l15) * 32 + l4 * 8;
    h16x8 s0 = c00[0] * w00 + c01[0] * w01 + c10[0] * w10 + c11[0] * w11;
    h16x8 s1 = c00[1] * w00 + c01[1] * w01 + c10[1] * w10 + c11[1] * w11;
    acc[0] = __builtin_amdgcn_mfma_f32_16x16x32_f16(s0, *(const h16x8*)(wq0 + 0 * 512), acc[0], 0, 0, 0);
    acc[1] = __builtin_amdgcn_mfma_f32_16x16x32_f16(s0, *(const h16x8*)(wq0 + 1 * 512), acc[1], 0, 0, 0);
    acc[2] = __builtin_amdgcn_mfma_f32_16x16x32_f16(s0, *(const h16x8*)(wq0 + 2 * 512), acc[2], 0, 0, 0);
    acc[3] = __builtin_amdgcn_mfma_f32_16x16x32_f16(s0, *(const h16x8*)(wq0 + 3 * 512), acc[3], 0, 0, 0);
    acc[0] = __builtin_amdgcn_mfma_f32_16x16x32_f16(s1, *(const h16x8*)(wq1 + 0 * 512), acc[0], 0, 0, 0);
    acc[1] = __builtin_amdgcn_mfma_f32_16x16x32_f16(s1, *(const h16x8*)(wq1 + 1 * 512), acc[1], 0, 0, 0);
    acc[2] = __builtin_amdgcn_mfma_f32_16x16x32_f16(s1, *(const h16x8*)(wq1 + 2 * 512), acc[2], 0, 0, 0);
    acc[3] = __builtin_amdgcn_mfma_f32_16x16x32_f16(s1, *(const h16x8*)(wq1 + 3 * 512), acc[3], 0, 0, 0);
  }
#undef OFFE

  float* outb = out + (size_t)b * CC * HWSZ;
#pragma unroll
  for (int og = 0; og < 4; ++og) {
    int o = og * 16 + l15;
    float bv = db[o];
    f32x4 st;
#pragma unroll
    for (int r = 0; r < 4; ++r) st[r] = fmaxf(acc[og][r] + bv, 0.f);
    *(f32x4*)(outb + (size_t)o * HWSZ + p0 + l4 * 4) = st;
  }
}

extern "C" void kernel_launch(void* const* d_in, const int* in_sizes, int n_in,
                              void* d_out, int out_size, void* d_ws, size_t ws_size,
                              hipStream_t stream) {
  const float* x     = (const float*)d_in[0];
  const float* bsize = (const float*)d_in[1];
  const float* gw1   = (const float*)d_in[2];
  const float* gb1   = (const float*)d_in[3];
  const float* gw2   = (const float*)d_in[4];
  const float* gb2   = (const float*)d_in[5];
  const float* lw1   = (const float*)d_in[6];
  const float* lb1   = (const float*)d_in[7];
  const float* lw2   = (const float*)d_in[8];
  const float* lb2   = (const float*)d_in[9];
  const float* fw1   = (const float*)d_in[10];
  const float* fb1   = (const float*)d_in[11];
  const float* fw2   = (const float*)d_in[12];
  const float* fb2   = (const float*)d_in[13];
  const float* dw    = (const float*)d_in[14];
  const float* db    = (const float*)d_in[15];
  float* out = (float*)d_out;

  // ws layout: gbuf(2KB) | xt f16 16.78MB | offc f16 [b][p][24] 6.29MB | dwq 72KB
  float* gbuf = (float*)d_ws;
  h16* xt   = (h16*)((char*)d_ws + 2048);
  h16* offc = (h16*)((char*)d_ws + 2048 + (size_t)BB * HWSZ * 64 * 2);
  h16* dwq  = (h16*)((char*)offc + (size_t)BB * HWSZ * 24 * 2);

  // d_out scratch: loff f16 CL @0 | cwpk @8.39MB | t1/t2 f16 CL @16.78MB
  h16* loff = (h16*)d_out;
  h16* cwpk = (h16*)d_out + 4194304;
  h16* t12  = (h16*)d_out + 8388608;
  const h16* lw1p = cwpk;
  const h16* lw2p = cwpk + 18432;
  const h16* fw1p = cwpk + 27648;
  const h16* fw2p = cwpk + 46080;

  g_mlp_kernel<<<1, 512, 0, stream>>>(bsize, gw1, gb1, gw2, gb2, gbuf);
  wprep_kernel<<<360, 256, 0, stream>>>(lw1, lw2, fw1, fw2, dw, cwpk, dwq);
  xtprep_kernel<<<512, 256, 0, stream>>>(x, xt);
  // t1 = relu(conv(x, lw1))
  conv_mfma_kernel<64, 2, false, true, 0><<<dim3(128, 8), 256, 0, stream>>>(
      xt, lw1p, lb1, nullptr, t12);
  // loff = conv(t1, lw2)
  conv_mfma_kernel<32, 1, false, false, 0><<<dim3(128, 8), 256, 0, stream>>>(
      t12, lw2p, lb2, nullptr, loff);
  // t2 = relu(conv(concat(g, loff), fw1))
  conv_mfma_kernel<32, 2, true, true, 0><<<dim3(128, 8), 256, 0, stream>>>(
      loff, fw1p, fb1, gbuf, t12);
  // offc = conv(t2, fw2), Cout=18, channel-last f16 stride 24
  conv_mfma_kernel<32, 1, false, false, 1><<<dim3(128, 8), 256, 0, stream>>>(
      t12, fw2p, fb2, nullptr, offc);
  // out = relu(deform_conv(x, offset, dw) + db)
  deform_mfma_kernel<<<dim3(256, 8), 256, 0, stream>>>(xt, offc, dwq, db, out);
}

// Round 7
// 138.739 us; speedup vs baseline: 8.6543x; 1.1471x over previous
//
#include <hip/hip_runtime.h>

#define BB 8
#define CC 64
#define HH 128
#define WW 128
#define HWSZ (HH*WW)

typedef _Float16 h16;
typedef __attribute__((ext_vector_type(8))) _Float16 h16x8;
typedef __attribute__((ext_vector_type(4))) _Float16 h16x4;
typedef __attribute__((ext_vector_type(2))) _Float16 h16x2;
typedef __attribute__((ext_vector_type(4))) float f32x4;

// ---------------- g MLP ----------------
__global__ __launch_bounds__(512) void g_mlp_kernel(
    const float* __restrict__ bsize, const float* __restrict__ gw1,
    const float* __restrict__ gb1, const float* __restrict__ gw2,
    const float* __restrict__ gb2, float* __restrict__ g) {
  __shared__ float h[BB][64];
  int t = threadIdx.x;
  if (t < BB * 64) {
    int b = t >> 6, i = t & 63;
    float v = fmaf(bsize[b * 2 + 0], gw1[i * 2 + 0],
                   fmaf(bsize[b * 2 + 1], gw1[i * 2 + 1], gb1[i]));
    h[b][i] = fmaxf(v, 0.f);
  }
  __syncthreads();
  if (t < BB * 32) {
    int b = t >> 5, j = t & 31;
    float acc = gb2[j];
#pragma unroll
    for (int i = 0; i < 64; ++i) acc = fmaf(h[b][i], gw2[j * 64 + i], acc);
    g[b * 32 + j] = acc;
  }
}

// ---- pack weights. Conv weights A-frag-packed [kt][cg][f][l15][l4][8]:
//   value = w[o = f*16+l15][c = cg*32+l4*8+e] at tap kt.
// cwq: lw1q(18432) @0, lw2q(9216) @18432, fw1q(18432) @27648, fw2q(9216) @46080.
// dwq: deform B-frag pack [kt][cg][og][l15][l4][8] (unchanged).
__device__ __forceinline__ void conv_pack(int j, int NCG, const float* w,
                                          int maxo, h16* dst) {
  int e = j & 7, l4 = (j >> 3) & 3, l15 = (j >> 5) & 15, f = (j >> 9) & 1;
  int cg = (j >> 10) & (NCG - 1), kt = (j >> 10) / NCG;
  int o = f * 16 + l15, c = cg * 32 + l4 * 8 + e;
  int CINw = NCG * 32;
  dst[j] = (o < maxo) ? (h16)w[(o * CINw + c) * 9 + kt] : (h16)0.f;
}

__global__ __launch_bounds__(256) void wprep_kernel(
    const float* __restrict__ lw1, const float* __restrict__ lw2,
    const float* __restrict__ fw1, const float* __restrict__ fw2,
    const float* __restrict__ dw, h16* __restrict__ cwq,
    h16* __restrict__ dwq) {
  int i = blockIdx.x * 256 + threadIdx.x;
  if (i < 18432) {
    conv_pack(i, 2, lw1, 32, cwq);
  } else if (i < 27648) {
    conv_pack(i - 18432, 1, lw2, 32, cwq + 18432);
  } else if (i < 46080) {
    conv_pack(i - 27648, 2, fw1, 32, cwq + 27648);
  } else if (i < 55296) {
    conv_pack(i - 46080, 1, fw2, 18, cwq + 46080);
  } else if (i < 55296 + 36864) {
    int j = i - 55296;
    int e = j & 7, l4 = (j >> 3) & 3, l15 = (j >> 5) & 15;
    int og = (j >> 9) & 3, cg = (j >> 11) & 1, kt = j >> 12;
    int o = og * 16 + l15, c = cg * 32 + l4 * 8 + e;
    dwq[j] = (h16)dw[(o * 64 + c) * 9 + kt];
  }
}

// ---- x -> channel-last f16: xt[b][p][64] ----
__global__ __launch_bounds__(256) void xtprep_kernel(
    const float* __restrict__ x, h16* __restrict__ xt) {
  int t = blockIdx.x * 256 + threadIdx.x;
  int b = t >> 14, p = t & 16383;
  const float* xb = x + (size_t)b * 64 * HWSZ + p;
  h16* ob = xt + (size_t)t * 64;
#pragma unroll
  for (int c0 = 0; c0 < 64; c0 += 8) {
    h16x8 v;
#pragma unroll
    for (int i = 0; i < 8; ++i) v[i] = (h16)xb[(size_t)(c0 + i) * HWSZ];
    *(h16x8*)(ob + c0) = v;
  }
}

// ---------------- conv 3x3 via MFMA + LDS row-tile ----------------
// block = (b, row h), 4 waves; wave: 32 px x 32 outs.
// LDS: rows h-1..h+1 channel-last, slot-swizzled s^(px&(NS-1)).
// A-frags from cwq (coalesced 1KB bursts). GFUSE: cg=0 = constant g frag.
template <int NCG, bool GFUSE, bool RELU, int OMODE>
__global__ __launch_bounds__(256) void conv_mfma_kernel(
    const h16* __restrict__ in, const h16* __restrict__ cwq,
    const float* __restrict__ bias, const float* __restrict__ g,
    h16* __restrict__ outv) {
  constexpr int CINS = GFUSE ? 32 : NCG * 32;  // staged channels
  constexpr int NS = CINS / 8;
  constexpr int LOG2NS = (NS == 8) ? 3 : 2;
  __shared__ __align__(16) h16 sh[3 * 128 * CINS];
  const int b = blockIdx.y, h = blockIdx.x;
  const int lane = threadIdx.x & 63, wave = threadIdx.x >> 6;
  const int l15 = lane & 15, l4 = lane >> 4;
  const h16* inb = in + (size_t)b * HWSZ * CINS;

  // ---- stage rows h-1..h+1 (coalesced, swizzled) ----
  for (int q = threadIdx.x; q < 3 * 128 * NS; q += 256) {
    int s = q & (NS - 1), pr = q >> LOG2NS;  // pr = r*128+px
    int r = pr >> 7, px = pr & 127;
    int gy = min(max(h - 1 + r, 0), HH - 1);
    h16x8 v = *(const h16x8*)(inb + ((size_t)gy * WW + px) * CINS + s * 8);
    *(h16x8*)(sh + pr * CINS + ((s ^ (px & (NS - 1))) * 8)) = v;
  }

  const h16x8 zfr = {0, 0, 0, 0, 0, 0, 0, 0};
  h16x8 gfr = zfr;
  if (GFUSE) {
#pragma unroll
    for (int i = 0; i < 8; ++i) gfr[i] = (h16)g[b * 32 + l4 * 8 + i];
  }
  __syncthreads();

  f32x4 acc[2][2];
#pragma unroll
  for (int f = 0; f < 2; ++f)
#pragma unroll
    for (int j = 0; j < 2; ++j) acc[f][j] = (f32x4){0.f, 0.f, 0.f, 0.f};

#pragma unroll
  for (int kt = 0; kt < 9; ++kt) {
    const int ki = kt / 3 - 1, kj = kt % 3 - 1;
    const int y = h + ki;
    const bool yok = (unsigned)y < HH;
    const int r = ki + 1;
    int xs[2];
    bool ok[2];
#pragma unroll
    for (int j = 0; j < 2; ++j) {
      int xx = wave * 32 + j * 16 + l15 + kj;
      ok[j] = yok && ((unsigned)xx < WW);
      xs[j] = min(max(xx, 0), WW - 1);
    }
#pragma unroll
    for (int cg = 0; cg < NCG; ++cg) {
      const h16* aq = cwq + (size_t)((kt * NCG + cg) * 2) * 512 + l15 * 32 + l4 * 8;
      h16x8 afr0 = *(const h16x8*)(aq);
      h16x8 afr1 = *(const h16x8*)(aq + 512);
#pragma unroll
      for (int j = 0; j < 2; ++j) {
        h16x8 bv;
        if (GFUSE && cg == 0) {
          bv = ok[j] ? gfr : zfr;
        } else {
          const int s = (!GFUSE && NCG == 2) ? cg * 4 + l4 : l4;
          h16x8 ld = *(const h16x8*)(sh + (r * 128 + xs[j]) * CINS +
                                     ((s ^ (xs[j] & (NS - 1))) * 8));
          bv = ok[j] ? ld : zfr;
        }
        acc[0][j] = __builtin_amdgcn_mfma_f32_16x16x32_f16(afr0, bv, acc[0][j], 0, 0, 0);
        acc[1][j] = __builtin_amdgcn_mfma_f32_16x16x32_f16(afr1, bv, acc[1][j], 0, 0, 0);
      }
    }
  }
  if (OMODE == 0) {
    h16* ob = outv + (size_t)b * HWSZ * 32;
#pragma unroll
    for (int f = 0; f < 2; ++f)
#pragma unroll
      for (int j = 0; j < 2; ++j) {
        int p = h * WW + wave * 32 + j * 16 + l15;
        int o0 = f * 16 + l4 * 4;
        h16x4 st;
#pragma unroll
        for (int r2 = 0; r2 < 4; ++r2) {
          float v = acc[f][j][r2] + bias[o0 + r2];
          if (RELU) v = fmaxf(v, 0.f);
          st[r2] = (h16)v;
        }
        *(h16x4*)(ob + (size_t)p * 32 + o0) = st;
      }
  } else {
    h16* ob = outv + (size_t)b * HWSZ * 24;
#pragma unroll
    for (int j = 0; j < 2; ++j) {
      int p = h * WW + wave * 32 + j * 16 + l15;
      {
        int o0 = l4 * 4;
        h16x4 st;
#pragma unroll
        for (int r2 = 0; r2 < 4; ++r2) st[r2] = (h16)(acc[0][j][r2] + bias[o0 + r2]);
        *(h16x4*)(ob + (size_t)p * 24 + o0) = st;
      }
      if (l4 == 0) {
        h16x2 st2;
        st2[0] = (h16)(acc[1][j][0] + bias[16]);
        st2[1] = (h16)(acc[1][j][1] + bias[17]);
        *(h16x2*)(ob + (size_t)p * 24 + 16) = st2;
      }
    }
  }
}

// ---------------- deformable conv via MFMA + LDS x-tile (unchanged R6) ----------------
__global__ __launch_bounds__(256) void deform_mfma_kernel(
    const h16* __restrict__ xt, const h16* __restrict__ offc,
    const h16* __restrict__ dwq, const float* __restrict__ db,
    float* __restrict__ out) {
  __shared__ __align__(16) h16 sh[5 * 72 * 64];
  const int b = blockIdx.y;
  const int h = blockIdx.x >> 1;
  const int halfx = (blockIdx.x & 1) * 64;
  const int x_lo = halfx - 4;
  const int lane = threadIdx.x & 63, wave = threadIdx.x >> 6;
  const int l15 = lane & 15, l4 = lane >> 4;
  const int wx = halfx + wave * 16;
  const int p0 = h * WW + wx;
  const int myw = wx + l15;
  const int mypix = p0 + l15;
  const h16* xb = xt + (size_t)b * HWSZ * 64;

#pragma unroll
  for (int it = 0; it < 12; ++it) {
    int q = it * 256 + threadIdx.x;
    if (q < 2880) {
      int s = q & 7, pr = q >> 3;
      int r = pr / 72, i = pr - r * 72;
      int gy = min(max(h - 2 + r, 0), HH - 1);
      int gx = min(max(x_lo + i, 0), WW - 1);
      h16x8 v = *(const h16x8*)(xb + ((size_t)gy * WW + gx) * 64 + s * 8);
      *(h16x8*)(sh + pr * 64 + ((s ^ (i & 7)) * 8)) = v;
    }
  }

  const h16* offp = offc + ((size_t)b * HWSZ + mypix) * 24;
  h16x8 offv0 = *(const h16x8*)(offp);
  h16x8 offv1 = *(const h16x8*)(offp + 8);
  h16x8 offv2 = *(const h16x8*)(offp + 16);
  __syncthreads();

#define OFFE(e) ((e) < 8 ? (float)offv0[(e) & 7] : (e) < 16 ? (float)offv1[(e) & 7] : (float)offv2[(e) & 7])

  f32x4 acc[4];
#pragma unroll
  for (int og = 0; og < 4; ++og) acc[og] = (f32x4){0.f, 0.f, 0.f, 0.f};

#pragma unroll
  for (int kt = 0; kt < 9; ++kt) {
    const int ki = kt / 3 - 1, kj = kt % 3 - 1;
    float py = (float)(h + ki) + OFFE(2 * kt);
    float px = (float)(myw + kj) + OFFE(2 * kt + 1);
    float y0f = floorf(py), x0f = floorf(px);
    float wy1 = py - y0f, wy0 = 1.f - wy1;
    float wx1 = px - x0f, wx0 = 1.f - wx1;
    int y0 = (int)y0f, x0i = (int)x0f;
    int y1 = y0 + 1, x1i = x0i + 1;
    bool y0ok = (unsigned)y0 < HH, y1ok = (unsigned)y1 < HH;
    bool x0ok = (unsigned)x0i < WW, x1ok = (unsigned)x1i < WW;
    h16 w00 = (h16)((y0ok && x0ok) ? wy0 * wx0 : 0.f);
    h16 w01 = (h16)((y0ok && x1ok) ? wy0 * wx1 : 0.f);
    h16 w10 = (h16)((y1ok && x0ok) ? wy1 * wx0 : 0.f);
    h16 w11 = (h16)((y1ok && x1ok) ? wy1 * wx1 : 0.f);
    int y0c = min(max(y0, 0), HH - 1), y1c = min(max(y1, 0), HH - 1);
    int x0c = min(max(x0i, 0), WW - 1), x1c = min(max(x1i, 0), WW - 1);
    int ty0u = y0c - (h - 2), ty1u = y1c - (h - 2);
    int tx0u = x0c - x_lo, tx1u = x1c - x_lo;
    bool fast = ((unsigned)ty0u <= 4u) & ((unsigned)ty1u <= 4u) &
                ((unsigned)tx0u <= 71u) & ((unsigned)tx1u <= 71u);
    int ty0 = min(max(ty0u, 0), 4), ty1 = min(max(ty1u, 0), 4);
    int tx0 = min(max(tx0u, 0), 71), tx1 = min(max(tx1u, 0), 71);
    int pr00 = (ty0 * 72 + tx0) * 64, pr01 = (ty0 * 72 + tx1) * 64;
    int pr10 = (ty1 * 72 + tx0) * 64, pr11 = (ty1 * 72 + tx1) * 64;
    int sx0 = (tx0 & 7) * 8, sx1 = (tx1 & 7) * 8;
    h16x8 c00[2], c01[2], c10[2], c11[2];
#pragma unroll
    for (int cg = 0; cg < 2; ++cg) {
      int sb = (cg * 4 + l4) * 8;
      c00[cg] = *(const h16x8*)(sh + pr00 + (sb ^ sx0));
      c01[cg] = *(const h16x8*)(sh + pr01 + (sb ^ sx1));
      c10[cg] = *(const h16x8*)(sh + pr10 + (sb ^ sx0));
      c11[cg] = *(const h16x8*)(sh + pr11 + (sb ^ sx1));
    }
    if (!fast) {
      int i00 = y0c * WW + x0c, i01 = y0c * WW + x1c;
      int i10 = y1c * WW + x0c, i11 = y1c * WW + x1c;
#pragma unroll
      for (int cg = 0; cg < 2; ++cg) {
        const h16* cb = xb + cg * 32 + l4 * 8;
        c00[cg] = *(const h16x8*)(cb + (size_t)i00 * 64);
        c01[cg] = *(const h16x8*)(cb + (size_t)i01 * 64);
        c10[cg] = *(const h16x8*)(cb + (size_t)i10 * 64);
        c11[cg] = *(const h16x8*)(cb + (size_t)i11 * 64);
      }
    }
    const h16* wq0 = dwq + ((size_t)(kt * 2 + 0) * 64 + l15) * 32 + l4 * 8;
    const h16* wq1 = dwq + ((size_t)(kt * 2 + 1) * 64 + l15) * 32 + l4 * 8;
    h16x8 s0 = c00[0] * w00 + c01[0] * w01 + c10[0] * w10 + c11[0] * w11;
    h16x8 s1 = c00[1] * w00 + c01[1] * w01 + c10[1] * w10 + c11[1] * w11;
    acc[0] = __builtin_amdgcn_mfma_f32_16x16x32_f16(s0, *(const h16x8*)(wq0 + 0 * 512), acc[0], 0, 0, 0);
    acc[1] = __builtin_amdgcn_mfma_f32_16x16x32_f16(s0, *(const h16x8*)(wq0 + 1 * 512), acc[1], 0, 0, 0);
    acc[2] = __builtin_amdgcn_mfma_f32_16x16x32_f16(s0, *(const h16x8*)(wq0 + 2 * 512), acc[2], 0, 0, 0);
    acc[3] = __builtin_amdgcn_mfma_f32_16x16x32_f16(s0, *(const h16x8*)(wq0 + 3 * 512), acc[3], 0, 0, 0);
    acc[0] = __builtin_amdgcn_mfma_f32_16x16x32_f16(s1, *(const h16x8*)(wq1 + 0 * 512), acc[0], 0, 0, 0);
    acc[1] = __builtin_amdgcn_mfma_f32_16x16x32_f16(s1, *(const h16x8*)(wq1 + 1 * 512), acc[1], 0, 0, 0);
    acc[2] = __builtin_amdgcn_mfma_f32_16x16x32_f16(s1, *(const h16x8*)(wq1 + 2 * 512), acc[2], 0, 0, 0);
    acc[3] = __builtin_amdgcn_mfma_f32_16x16x32_f16(s1, *(const h16x8*)(wq1 + 3 * 512), acc[3], 0, 0, 0);
  }
#undef OFFE

  float* outb = out + (size_t)b * CC * HWSZ;
#pragma unroll
  for (int og = 0; og < 4; ++og) {
    int o = og * 16 + l15;
    float bv = db[o];
    f32x4 st;
#pragma unroll
    for (int r = 0; r < 4; ++r) st[r] = fmaxf(acc[og][r] + bv, 0.f);
    *(f32x4*)(outb + (size_t)o * HWSZ + p0 + l4 * 4) = st;
  }
}

extern "C" void kernel_launch(void* const* d_in, const int* in_sizes, int n_in,
                              void* d_out, int out_size, void* d_ws, size_t ws_size,
                              hipStream_t stream) {
  const float* x     = (const float*)d_in[0];
  const float* bsize = (const float*)d_in[1];
  const float* gw1   = (const float*)d_in[2];
  const float* gb1   = (const float*)d_in[3];
  const float* gw2   = (const float*)d_in[4];
  const float* gb2   = (const float*)d_in[5];
  const float* lw1   = (const float*)d_in[6];
  const float* lb1   = (const float*)d_in[7];
  const float* lw2   = (const float*)d_in[8];
  const float* lb2   = (const float*)d_in[9];
  const float* fw1   = (const float*)d_in[10];
  const float* fb1   = (const float*)d_in[11];
  const float* fw2   = (const float*)d_in[12];
  const float* fb2   = (const float*)d_in[13];
  const float* dw    = (const float*)d_in[14];
  const float* db    = (const float*)d_in[15];
  float* out = (float*)d_out;

  // ws layout: gbuf(2KB) | xt f16 16.78MB | offc f16 [b][p][24] 6.29MB | dwq 72KB
  float* gbuf = (float*)d_ws;
  h16* xt   = (h16*)((char*)d_ws + 2048);
  h16* offc = (h16*)((char*)d_ws + 2048 + (size_t)BB * HWSZ * 64 * 2);
  h16* dwq  = (h16*)((char*)offc + (size_t)BB * HWSZ * 24 * 2);

  // d_out scratch: loff f16 CL @0 | cwq @8.39MB | t1/t2 f16 CL @16.78MB
  h16* loff = (h16*)d_out;
  h16* cwq  = (h16*)d_out + 4194304;
  h16* t12  = (h16*)d_out + 8388608;
  const h16* lw1q = cwq;
  const h16* lw2q = cwq + 18432;
  const h16* fw1q = cwq + 27648;
  const h16* fw2q = cwq + 46080;

  g_mlp_kernel<<<1, 512, 0, stream>>>(bsize, gw1, gb1, gw2, gb2, gbuf);
  wprep_kernel<<<360, 256, 0, stream>>>(lw1, lw2, fw1, fw2, dw, cwq, dwq);
  xtprep_kernel<<<512, 256, 0, stream>>>(x, xt);
  // t1 = relu(conv(x, lw1))
  conv_mfma_kernel<2, false, true, 0><<<dim3(128, 8), 256, 0, stream>>>(
      xt, lw1q, lb1, nullptr, t12);
  // loff = conv(t1, lw2)
  conv_mfma_kernel<1, false, false, 0><<<dim3(128, 8), 256, 0, stream>>>(
      t12, lw2q, lb2, nullptr, loff);
  // t2 = relu(conv(concat(g, loff), fw1))
  conv_mfma_kernel<2, true, true, 0><<<dim3(128, 8), 256, 0, stream>>>(
      loff, fw1q, fb1, gbuf, t12);
  // offc = conv(t2, fw2), Cout=18, channel-last f16 stride 24
  conv_mfma_kernel<1, false, false, 1><<<dim3(128, 8), 256, 0, stream>>>(
      t12, fw2q, fb2, nullptr, offc);
  // out = relu(deform_conv(x, offset, dw) + db)
  deform_mfma_kernel<<<dim3(256, 8), 256, 0, stream>>>(xt, offc, dwq, db, out);
}

// Round 8
// 117.229 us; speedup vs baseline: 10.2422x; 1.1835x over previous
//
#include <hip/hip_runtime.h>

#define BB 8
#define CC 64
#define HH 128
#define WW 128
#define HWSZ (HH*WW)

typedef _Float16 h16;
typedef __attribute__((ext_vector_type(8))) _Float16 h16x8;
typedef __attribute__((ext_vector_type(4))) _Float16 h16x4;
typedef __attribute__((ext_vector_type(2))) _Float16 h16x2;
typedef __attribute__((ext_vector_type(4))) float f32x4;

// ---------------- g MLP ----------------
__global__ __launch_bounds__(512) void g_mlp_kernel(
    const float* __restrict__ bsize, const float* __restrict__ gw1,
    const float* __restrict__ gb1, const float* __restrict__ gw2,
    const float* __restrict__ gb2, float* __restrict__ g) {
  __shared__ float h[BB][64];
  int t = threadIdx.x;
  if (t < BB * 64) {
    int b = t >> 6, i = t & 63;
    float v = fmaf(bsize[b * 2 + 0], gw1[i * 2 + 0],
                   fmaf(bsize[b * 2 + 1], gw1[i * 2 + 1], gb1[i]));
    h[b][i] = fmaxf(v, 0.f);
  }
  __syncthreads();
  if (t < BB * 32) {
    int b = t >> 5, j = t & 31;
    float acc = gb2[j];
#pragma unroll
    for (int i = 0; i < 64; ++i) acc = fmaf(h[b][i], gw2[j * 64 + i], acc);
    g[b * 32 + j] = acc;
  }
}

// ---- pack weights (unchanged R7) ----
__device__ __forceinline__ void conv_pack(int j, int NCG, const float* w,
                                          int maxo, h16* dst) {
  int e = j & 7, l4 = (j >> 3) & 3, l15 = (j >> 5) & 15, f = (j >> 9) & 1;
  int cg = (j >> 10) & (NCG - 1), kt = (j >> 10) / NCG;
  int o = f * 16 + l15, c = cg * 32 + l4 * 8 + e;
  int CINw = NCG * 32;
  dst[j] = (o < maxo) ? (h16)w[(o * CINw + c) * 9 + kt] : (h16)0.f;
}

__global__ __launch_bounds__(256) void wprep_kernel(
    const float* __restrict__ lw1, const float* __restrict__ lw2,
    const float* __restrict__ fw1, const float* __restrict__ fw2,
    const float* __restrict__ dw, h16* __restrict__ cwq,
    h16* __restrict__ dwq) {
  int i = blockIdx.x * 256 + threadIdx.x;
  if (i < 18432) {
    conv_pack(i, 2, lw1, 32, cwq);
  } else if (i < 27648) {
    conv_pack(i - 18432, 1, lw2, 32, cwq + 18432);
  } else if (i < 46080) {
    conv_pack(i - 27648, 2, fw1, 32, cwq + 27648);
  } else if (i < 55296) {
    conv_pack(i - 46080, 1, fw2, 18, cwq + 46080);
  } else if (i < 55296 + 36864) {
    int j = i - 55296;
    int e = j & 7, l4 = (j >> 3) & 3, l15 = (j >> 5) & 15;
    int og = (j >> 9) & 3, cg = (j >> 11) & 1, kt = j >> 12;
    int o = og * 16 + l15, c = cg * 32 + l4 * 8 + e;
    dwq[j] = (h16)dw[(o * 64 + c) * 9 + kt];
  }
}

// ---- x -> channel-last f16, XCD-affine (batch b on XCD b) ----
__global__ __launch_bounds__(256) void xtprep_kernel(
    const float* __restrict__ x, h16* __restrict__ xt) {
  int wg = (blockIdx.x & 7) * 64 + (blockIdx.x >> 3);
  int t = wg * 256 + threadIdx.x;
  int b = t >> 14, p = t & 16383;
  const float* xb = x + (size_t)b * 64 * HWSZ + p;
  h16* ob = xt + (size_t)t * 64;
#pragma unroll
  for (int c0 = 0; c0 < 64; c0 += 8) {
    h16x8 v;
#pragma unroll
    for (int i = 0; i < 8; ++i) v[i] = (h16)xb[(size_t)(c0 + i) * HWSZ];
    *(h16x8*)(ob + c0) = v;
  }
}

// ---------------- conv 3x3 via MFMA + LDS row-tile (R7) + XCD swizzle ----------------
template <int NCG, bool GFUSE, bool RELU, int OMODE>
__global__ __launch_bounds__(256) void conv_mfma_kernel(
    const h16* __restrict__ in, const h16* __restrict__ cwq,
    const float* __restrict__ bias, const float* __restrict__ g,
    h16* __restrict__ outv) {
  constexpr int CINS = GFUSE ? 32 : NCG * 32;
  constexpr int NS = CINS / 8;
  constexpr int LOG2NS = (NS == 8) ? 3 : 2;
  __shared__ __align__(16) h16 sh[3 * 128 * CINS];
  const int wgid = (blockIdx.x & 7) * 128 + (blockIdx.x >> 3);
  const int b = wgid >> 7, h = wgid & 127;
  const int lane = threadIdx.x & 63, wave = threadIdx.x >> 6;
  const int l15 = lane & 15, l4 = lane >> 4;
  const h16* inb = in + (size_t)b * HWSZ * CINS;

  for (int q = threadIdx.x; q < 3 * 128 * NS; q += 256) {
    int s = q & (NS - 1), pr = q >> LOG2NS;
    int r = pr >> 7, px = pr & 127;
    int gy = min(max(h - 1 + r, 0), HH - 1);
    h16x8 v = *(const h16x8*)(inb + ((size_t)gy * WW + px) * CINS + s * 8);
    *(h16x8*)(sh + pr * CINS + ((s ^ (px & (NS - 1))) * 8)) = v;
  }

  const h16x8 zfr = {0, 0, 0, 0, 0, 0, 0, 0};
  h16x8 gfr = zfr;
  if (GFUSE) {
#pragma unroll
    for (int i = 0; i < 8; ++i) gfr[i] = (h16)g[b * 32 + l4 * 8 + i];
  }
  __syncthreads();

  f32x4 acc[2][2];
#pragma unroll
  for (int f = 0; f < 2; ++f)
#pragma unroll
    for (int j = 0; j < 2; ++j) acc[f][j] = (f32x4){0.f, 0.f, 0.f, 0.f};

#pragma unroll
  for (int kt = 0; kt < 9; ++kt) {
    const int ki = kt / 3 - 1, kj = kt % 3 - 1;
    const int y = h + ki;
    const bool yok = (unsigned)y < HH;
    const int r = ki + 1;
    int xs[2];
    bool ok[2];
#pragma unroll
    for (int j = 0; j < 2; ++j) {
      int xx = wave * 32 + j * 16 + l15 + kj;
      ok[j] = yok && ((unsigned)xx < WW);
      xs[j] = min(max(xx, 0), WW - 1);
    }
#pragma unroll
    for (int cg = 0; cg < NCG; ++cg) {
      const h16* aq = cwq + (size_t)((kt * NCG + cg) * 2) * 512 + l15 * 32 + l4 * 8;
      h16x8 afr0 = *(const h16x8*)(aq);
      h16x8 afr1 = *(const h16x8*)(aq + 512);
#pragma unroll
      for (int j = 0; j < 2; ++j) {
        h16x8 bv;
        if (GFUSE && cg == 0) {
          bv = ok[j] ? gfr : zfr;
        } else {
          const int s = (!GFUSE && NCG == 2) ? cg * 4 + l4 : l4;
          h16x8 ld = *(const h16x8*)(sh + (r * 128 + xs[j]) * CINS +
                                     ((s ^ (xs[j] & (NS - 1))) * 8));
          bv = ok[j] ? ld : zfr;
        }
        acc[0][j] = __builtin_amdgcn_mfma_f32_16x16x32_f16(afr0, bv, acc[0][j], 0, 0, 0);
        acc[1][j] = __builtin_amdgcn_mfma_f32_16x16x32_f16(afr1, bv, acc[1][j], 0, 0, 0);
      }
    }
  }
  if (OMODE == 0) {
    h16* ob = outv + (size_t)b * HWSZ * 32;
#pragma unroll
    for (int f = 0; f < 2; ++f)
#pragma unroll
      for (int j = 0; j < 2; ++j) {
        int p = h * WW + wave * 32 + j * 16 + l15;
        int o0 = f * 16 + l4 * 4;
        h16x4 st;
#pragma unroll
        for (int r2 = 0; r2 < 4; ++r2) {
          float v = acc[f][j][r2] + bias[o0 + r2];
          if (RELU) v = fmaxf(v, 0.f);
          st[r2] = (h16)v;
        }
        *(h16x4*)(ob + (size_t)p * 32 + o0) = st;
      }
  } else {
    h16* ob = outv + (size_t)b * HWSZ * 24;
#pragma unroll
    for (int j = 0; j < 2; ++j) {
      int p = h * WW + wave * 32 + j * 16 + l15;
      {
        int o0 = l4 * 4;
        h16x4 st;
#pragma unroll
        for (int r2 = 0; r2 < 4; ++r2) st[r2] = (h16)(acc[0][j][r2] + bias[o0 + r2]);
        *(h16x4*)(ob + (size_t)p * 24 + o0) = st;
      }
      if (l4 == 0) {
        h16x2 st2;
        st2[0] = (h16)(acc[1][j][0] + bias[16]);
        st2[1] = (h16)(acc[1][j][1] + bias[17]);
        *(h16x2*)(ob + (size_t)p * 24 + 16) = st2;
      }
    }
  }
}

// ---------------- deformable conv: LDS x-tile + 2-deep tap pipeline ----------------
__global__ __launch_bounds__(256) void deform_mfma_kernel(
    const h16* __restrict__ xt, const h16* __restrict__ offc,
    const h16* __restrict__ dwq, const float* __restrict__ db,
    float* __restrict__ out) {
  __shared__ __align__(16) h16 sh[5 * 72 * 64];
  const int wgid = (blockIdx.x & 7) * 256 + (blockIdx.x >> 3);
  const int b = wgid >> 8;
  const int rh = wgid & 255;
  const int h = rh >> 1;
  const int halfx = (rh & 1) * 64;
  const int x_lo = halfx - 4;
  const int lane = threadIdx.x & 63, wave = threadIdx.x >> 6;
  const int l15 = lane & 15, l4 = lane >> 4;
  const int wx = halfx + wave * 16;
  const int p0 = h * WW + wx;
  const int myw = wx + l15;
  const int mypix = p0 + l15;
  const h16* xb = xt + (size_t)b * HWSZ * 64;

#pragma unroll
  for (int it = 0; it < 12; ++it) {
    int q = it * 256 + threadIdx.x;
    if (q < 2880) {
      int s = q & 7, pr = q >> 3;
      int r = pr / 72, i = pr - r * 72;
      int gy = min(max(h - 2 + r, 0), HH - 1);
      int gx = min(max(x_lo + i, 0), WW - 1);
      h16x8 v = *(const h16x8*)(xb + ((size_t)gy * WW + gx) * 64 + s * 8);
      *(h16x8*)(sh + pr * 64 + ((s ^ (i & 7)) * 8)) = v;
    }
  }

  const h16* offp = offc + ((size_t)b * HWSZ + mypix) * 24;
  h16x8 offv0 = *(const h16x8*)(offp);
  h16x8 offv1 = *(const h16x8*)(offp + 8);
  h16x8 offv2 = *(const h16x8*)(offp + 16);
  __syncthreads();

#define OFFE(e) ((e) < 8 ? (float)offv0[(e) & 7] : (e) < 16 ? (float)offv1[(e) & 7] : (float)offv2[(e) & 7])

  f32x4 acc[4];
#pragma unroll
  for (int og = 0; og < 4; ++og) acc[og] = (f32x4){0.f, 0.f, 0.f, 0.f};

  h16x8 pc[2][2][4];  // [parity][cg][corner]
  h16x8 pw[2][8];     // [parity][cg*4+og]
  h16   pg[2][4];     // [parity][corner weight]

#define PREF(kt, par) do {                                                  \
    float py = (float)(h + (kt) / 3 - 1) + OFFE(2 * (kt));                  \
    float px = (float)(myw + (kt) % 3 - 1) + OFFE(2 * (kt) + 1);            \
    float y0f = floorf(py), x0f = floorf(px);                               \
    float wy1 = py - y0f, wy0 = 1.f - wy1;                                  \
    float wx1 = px - x0f, wx0 = 1.f - wx1;                                  \
    int y0 = (int)y0f, x0i = (int)x0f;                                      \
    int y1 = y0 + 1, x1i = x0i + 1;                                         \
    bool y0ok = (unsigned)y0 < HH, y1ok = (unsigned)y1 < HH;                \
    bool x0ok = (unsigned)x0i < WW, x1ok = (unsigned)x1i < WW;              \
    pg[par][0] = (h16)((y0ok && x0ok) ? wy0 * wx0 : 0.f);                   \
    pg[par][1] = (h16)((y0ok && x1ok) ? wy0 * wx1 : 0.f);                   \
    pg[par][2] = (h16)((y1ok && x0ok) ? wy1 * wx0 : 0.f);                   \
    pg[par][3] = (h16)((y1ok && x1ok) ? wy1 * wx1 : 0.f);                   \
    int y0c = min(max(y0, 0), HH - 1), y1c = min(max(y1, 0), HH - 1);       \
    int x0c = min(max(x0i, 0), WW - 1), x1c = min(max(x1i, 0), WW - 1);     \
    int ty0u = y0c - (h - 2), ty1u = y1c - (h - 2);                         \
    int tx0u = x0c - x_lo, tx1u = x1c - x_lo;                               \
    bool fast = ((unsigned)ty0u <= 4u) & ((unsigned)ty1u <= 4u) &           \
                ((unsigned)tx0u <= 71u) & ((unsigned)tx1u <= 71u);          \
    int ty0 = min(max(ty0u, 0), 4), ty1 = min(max(ty1u, 0), 4);             \
    int tx0 = min(max(tx0u, 0), 71), tx1 = min(max(tx1u, 0), 71);           \
    int pr00 = (ty0 * 72 + tx0) * 64, pr01 = (ty0 * 72 + tx1) * 64;         \
    int pr10 = (ty1 * 72 + tx0) * 64, pr11 = (ty1 * 72 + tx1) * 64;         \
    int sx0 = (tx0 & 7) * 8, sx1 = (tx1 & 7) * 8;                           \
    _Pragma("unroll")                                                       \
    for (int cg = 0; cg < 2; ++cg) {                                        \
      int sb = (cg * 4 + l4) * 8;                                           \
      pc[par][cg][0] = *(const h16x8*)(sh + pr00 + (sb ^ sx0));             \
      pc[par][cg][1] = *(const h16x8*)(sh + pr01 + (sb ^ sx1));             \
      pc[par][cg][2] = *(const h16x8*)(sh + pr10 + (sb ^ sx0));             \
      pc[par][cg][3] = *(const h16x8*)(sh + pr11 + (sb ^ sx1));             \
    }                                                                       \
    if (!fast) {                                                            \
      int i00 = y0c * WW + x0c, i01 = y0c * WW + x1c;                       \
      int i10 = y1c * WW + x0c, i11 = y1c * WW + x1c;                       \
      _Pragma("unroll")                                                     \
      for (int cg = 0; cg < 2; ++cg) {                                      \
        const h16* cb = xb + cg * 32 + l4 * 8;                              \
        pc[par][cg][0] = *(const h16x8*)(cb + (size_t)i00 * 64);            \
        pc[par][cg][1] = *(const h16x8*)(cb + (size_t)i01 * 64);            \
        pc[par][cg][2] = *(const h16x8*)(cb + (size_t)i10 * 64);            \
        pc[par][cg][3] = *(const h16x8*)(cb + (size_t)i11 * 64);            \
      }                                                                     \
    }                                                                       \
    const h16* wq0 = dwq + ((size_t)((kt) * 2 + 0) * 64 + l15) * 32 + l4 * 8; \
    const h16* wq1 = dwq + ((size_t)((kt) * 2 + 1) * 64 + l15) * 32 + l4 * 8; \
    pw[par][0] = *(const h16x8*)(wq0 + 0 * 512);                            \
    pw[par][1] = *(const h16x8*)(wq0 + 1 * 512);                            \
    pw[par][2] = *(const h16x8*)(wq0 + 2 * 512);                            \
    pw[par][3] = *(const h16x8*)(wq0 + 3 * 512);                            \
    pw[par][4] = *(const h16x8*)(wq1 + 0 * 512);                            \
    pw[par][5] = *(const h16x8*)(wq1 + 1 * 512);                            \
    pw[par][6] = *(const h16x8*)(wq1 + 2 * 512);                            \
    pw[par][7] = *(const h16x8*)(wq1 + 3 * 512);                            \
  } while (0)

#define CONS(par) do {                                                      \
    h16 w00 = pg[par][0], w01 = pg[par][1], w10 = pg[par][2], w11 = pg[par][3]; \
    h16x8 s0 = pc[par][0][0] * w00 + pc[par][0][1] * w01                    \
             + pc[par][0][2] * w10 + pc[par][0][3] * w11;                   \
    h16x8 s1 = pc[par][1][0] * w00 + pc[par][1][1] * w01                    \
             + pc[par][1][2] * w10 + pc[par][1][3] * w11;                   \
    acc[0] = __builtin_amdgcn_mfma_f32_16x16x32_f16(s0, pw[par][0], acc[0], 0, 0, 0); \
    acc[1] = __builtin_amdgcn_mfma_f32_16x16x32_f16(s0, pw[par][1], acc[1], 0, 0, 0); \
    acc[2] = __builtin_amdgcn_mfma_f32_16x16x32_f16(s0, pw[par][2], acc[2], 0, 0, 0); \
    acc[3] = __builtin_amdgcn_mfma_f32_16x16x32_f16(s0, pw[par][3], acc[3], 0, 0, 0); \
    acc[0] = __builtin_amdgcn_mfma_f32_16x16x32_f16(s1, pw[par][4], acc[0], 0, 0, 0); \
    acc[1] = __builtin_amdgcn_mfma_f32_16x16x32_f16(s1, pw[par][5], acc[1], 0, 0, 0); \
    acc[2] = __builtin_amdgcn_mfma_f32_16x16x32_f16(s1, pw[par][6], acc[2], 0, 0, 0); \
    acc[3] = __builtin_amdgcn_mfma_f32_16x16x32_f16(s1, pw[par][7], acc[3], 0, 0, 0); \
  } while (0)

  PREF(0, 0);
  PREF(1, 1);
  CONS(0);
  PREF(2, 0);
  CONS(1);
  PREF(3, 1);
  CONS(0);
  PREF(4, 0);
  CONS(1);
  PREF(5, 1);
  CONS(0);
  PREF(6, 0);
  CONS(1);
  PREF(7, 1);
  CONS(0);
  PREF(8, 0);
  CONS(1);
  CONS(0);
#undef PREF
#undef CONS
#undef OFFE

  float* outb = out + (size_t)b * CC * HWSZ;
#pragma unroll
  for (int og = 0; og < 4; ++og) {
    int o = og * 16 + l15;
    float bv = db[o];
    f32x4 st;
#pragma unroll
    for (int r = 0; r < 4; ++r) st[r] = fmaxf(acc[og][r] + bv, 0.f);
    *(f32x4*)(outb + (size_t)o * HWSZ + p0 + l4 * 4) = st;
  }
}

extern "C" void kernel_launch(void* const* d_in, const int* in_sizes, int n_in,
                              void* d_out, int out_size, void* d_ws, size_t ws_size,
                              hipStream_t stream) {
  const float* x     = (const float*)d_in[0];
  const float* bsize = (const float*)d_in[1];
  const float* gw1   = (const float*)d_in[2];
  const float* gb1   = (const float*)d_in[3];
  const float* gw2   = (const float*)d_in[4];
  const float* gb2   = (const float*)d_in[5];
  const float* lw1   = (const float*)d_in[6];
  const float* lb1   = (const float*)d_in[7];
  const float* lw2   = (const float*)d_in[8];
  const float* lb2   = (const float*)d_in[9];
  const float* fw1   = (const float*)d_in[10];
  const float* fb1   = (const float*)d_in[11];
  const float* fw2   = (const float*)d_in[12];
  const float* fb2   = (const float*)d_in[13];
  const float* dw    = (const float*)d_in[14];
  const float* db    = (const float*)d_in[15];
  float* out = (float*)d_out;

  // ws layout: gbuf(2KB) | xt f16 16.78MB | offc f16 [b][p][24] 6.29MB | dwq 72KB
  float* gbuf = (float*)d_ws;
  h16* xt   = (h16*)((char*)d_ws + 2048);
  h16* offc = (h16*)((char*)d_ws + 2048 + (size_t)BB * HWSZ * 64 * 2);
  h16* dwq  = (h16*)((char*)offc + (size_t)BB * HWSZ * 24 * 2);

  // d_out scratch: loff f16 CL @0 | cwq @8.39MB | t1/t2 f16 CL @16.78MB
  h16* loff = (h16*)d_out;
  h16* cwq  = (h16*)d_out + 4194304;
  h16* t12  = (h16*)d_out + 8388608;
  const h16* lw1q = cwq;
  const h16* lw2q = cwq + 18432;
  const h16* fw1q = cwq + 27648;
  const h16* fw2q = cwq + 46080;

  g_mlp_kernel<<<1, 512, 0, stream>>>(bsize, gw1, gb1, gw2, gb2, gbuf);
  wprep_kernel<<<360, 256, 0, stream>>>(lw1, lw2, fw1, fw2, dw, cwq, dwq);
  xtprep_kernel<<<512, 256, 0, stream>>>(x, xt);
  // t1 = relu(conv(x, lw1))
  conv_mfma_kernel<2, false, true, 0><<<1024, 256, 0, stream>>>(
      xt, lw1q, lb1, nullptr, t12);
  // loff = conv(t1, lw2)
  conv_mfma_kernel<1, false, false, 0><<<1024, 256, 0, stream>>>(
      t12, lw2q, lb2, nullptr, loff);
  // t2 = relu(conv(concat(g, loff), fw1))
  conv_mfma_kernel<2, true, true, 0><<<1024, 256, 0, stream>>>(
      loff, fw1q, fb1, gbuf, t12);
  // offc = conv(t2, fw2), Cout=18, channel-last f16 stride 24
  conv_mfma_kernel<1, false, false, 1><<<1024, 256, 0, stream>>>(
      t12, fw2q, fb2, nullptr, offc);
  // out = relu(deform_conv(x, offset, dw) + db)
  deform_mfma_kernel<<<2048, 256, 0, stream>>>(xt, offc, dwq, db, out);
}